// Round 5
// baseline (1687.799 us; speedup 1.0000x reference)
//
#include <hip/hip_runtime.h>
#include <hip/hip_fp16.h>

#define N_NODES 100000
#define N_EDGES 1600000
#define NBUCKET 196          // ceil(100000 / 512)
#define CAP     8960         // per-bucket capacity: mean 8163, sigma 90 -> +8.8 sigma
#define EPB     6250         // edges per block in partition (256 blocks)
#define VB_GEMM ((N_NODES + 63) / 64)   // 1563 gemm tiles
#define VB_AGG  ((N_NODES + 7) / 8)     // 12500 agg virtual blocks

typedef _Float16 half8 __attribute__((ext_vector_type(8)));
typedef float float4v __attribute__((ext_vector_type(4)));

// acc += (float)lo_half(w) / hi_half(w) in ONE VALU op (bit-identical to cvt+add).
__device__ __forceinline__ void fmix_lo(float& a, unsigned int w, float one) {
    asm("v_fma_mix_f32 %0, %1, %2, %0 op_sel:[0,0,0] op_sel_hi:[1,0,0]"
        : "+v"(a) : "v"(w), "v"(one));
}
__device__ __forceinline__ void fmix_hi(float& a, unsigned int w, float one) {
    asm("v_fma_mix_f32 %0, %1, %2, %0 op_sel:[1,0,0] op_sel_hi:[1,0,0]"
        : "+v"(a) : "v"(w), "v"(one));
}

// ---------------- lightweight grid barrier: 1 poller/block, s_sleep backoff.
// Per-phase dedicated counter (zeroed by host memset before launch) -> no reset race.
// Release: __syncthreads (block's stores vmcnt-drained to L2) + __threadfence (wbl2).
// Acquire: agent-scope load sees count==nb, then __threadfence (inv L1/L2) in ALL threads.
__device__ __forceinline__ void gbar(int* cnt, int nb) {
    __syncthreads();
    __threadfence();
    if (threadIdx.x == 0) {
        __hip_atomic_fetch_add(cnt, 1, __ATOMIC_RELEASE, __HIP_MEMORY_SCOPE_AGENT);
        while (__hip_atomic_load(cnt, __ATOMIC_ACQUIRE, __HIP_MEMORY_SCOPE_AGENT) < nb)
            __builtin_amdgcn_s_sleep(32);
    }
    __syncthreads();
    __threadfence();
}

// ---------------- phase bodies (shared by mega kernel and fallback wrappers)

__device__ __forceinline__ void wswz_one(int t, const float* __restrict__ W1,
                                         const float* __restrict__ W2, const float* __restrict__ W3,
                                         _Float16* __restrict__ wz1, _Float16* __restrict__ wz2,
                                         _Float16* __restrict__ wz3) {
    const float* W; _Float16* wsz; int BN;
    if (t < 2048)      { W = W1; wsz = wz1; BN = 128; }
    else if (t < 4096) { W = W2; wsz = wz2; BN = 128; t -= 2048; }
    else               { W = W3; wsz = wz3; BN = 64;  t -= 4096; }
    const int l = t & 63;
    const int kblk = (t >> 6) & 3;
    const int nt = t >> 8;
    const int krow = kblk * 32 + ((l >> 4) << 3);
    const int col = nt * 16 + (l & 15);
    _Float16 v[8];
#pragma unroll
    for (int j = 0; j < 8; ++j) v[j] = (_Float16)W[(krow + j) * BN + col];
    *(uint4*)&wsz[t << 3] = *(uint4*)v;
}

__device__ __forceinline__ void d_part(int vb, int tid, int* hist, int* basebkt,
                                       const int* __restrict__ src, const int* __restrict__ dst,
                                       int* __restrict__ bcur, int* __restrict__ ebuf, int E) {
    __syncthreads();   // protect LDS reuse across virtual blocks / phases
    if (tid < 200) hist[tid] = 0;
    __syncthreads();
    const int e0 = vb * EPB, e1 = min(e0 + EPB, E);
    for (int e = e0 + tid; e < e1; e += 256) atomicAdd(&hist[dst[e] >> 9], 1);
    __syncthreads();
    if (tid < NBUCKET) {
        int h = hist[tid];
        basebkt[tid] = tid * CAP + (h ? atomicAdd(&bcur[tid], h) : 0);
    }
    __syncthreads();
    if (tid < 200) hist[tid] = 0;
    __syncthreads();
    for (int e = e0 + tid; e < e1; e += 256) {
        int d = dst[e];
        int bk = d >> 9;
        int o = atomicAdd(&hist[bk], 1);
        ebuf[basebkt[bk] + o] = (src[e] << 9) | (d & 511);
    }
}

__device__ __forceinline__ void d_bsort(int vb, int tid, int* cnt, int* offs,
                                        const int* __restrict__ ebuf, const int* __restrict__ bcur,
                                        int* __restrict__ adj, int* __restrict__ stv,
                                        int* __restrict__ deg, float* __restrict__ dinv, int N) {
    __syncthreads();
    const int base = vb * CAP;
    const int n_b = min(bcur[vb], CAP);
    const int node0 = vb << 9;
    cnt[tid] = 0; cnt[tid + 256] = 0;
    __syncthreads();
    for (int i = tid; i < n_b; i += 256)
        atomicAdd(&cnt[ebuf[base + i] & 511], 1);
    __syncthreads();
    if (tid < 64) {  // wave-0 exclusive scan of 512
        int v[8], tot = 0;
#pragma unroll
        for (int j = 0; j < 8; ++j) { int t = cnt[tid * 8 + j]; v[j] = tot; tot += t; }
        int inc = tot;
#pragma unroll
        for (int d = 1; d < 64; d <<= 1) {
            int u = __shfl_up(inc, d, 64);
            if (tid >= d) inc += u;
        }
        const int excl = inc - tot;
#pragma unroll
        for (int j = 0; j < 8; ++j) offs[tid * 8 + j] = excl + v[j];
    }
    __syncthreads();
#pragma unroll
    for (int h = 0; h < 2; ++h) {
        int local = tid + h * 256;
        int node = node0 + local;
        if (node < N) {
            stv[node] = base + offs[local];
            deg[node] = cnt[local];
            dinv[node] = rsqrtf((float)(cnt[local] + 1));
        }
    }
    __syncthreads();
    for (int i = tid; i < n_b; i += 256) {  // offs doubles as cursor
        int pk = ebuf[base + i];
        int pos = atomicAdd(&offs[pk & 511], 1);
        adj[base + pos] = pk >> 9;
    }
}

// MFMA GEMM tile: tp[i][:] = fp16( dinv[i] * (X[i][:] @ W) ), K=128
template <int BN, bool AFP16>
__device__ __forceinline__ void d_gemm(int vb, int tid, _Float16* smem,
                                       const void* __restrict__ Xv, const _Float16* __restrict__ wsz,
                                       const float* __restrict__ dinv, __half* __restrict__ out, int N) {
    constexpr int NT = BN / 16;
    constexpr int PAD = 8;
    __syncthreads();   // protect smem reuse across virtual blocks / phases
    for (int i = tid; i < BN * 16; i += 256)
        *(uint4*)&smem[i << 3] = *(const uint4*)&wsz[i << 3];

    const int w = tid >> 6;
    const int lane = tid & 63;
    const int q = lane >> 4;
    const int m = lane & 15;
    const int row0 = vb * 64;
    const int arow = row0 + w * 16 + m;
    const int arowc = arow < N ? arow : N - 1;

    float4v acc[NT];
#pragma unroll
    for (int nt = 0; nt < NT; ++nt) acc[nt] = (float4v){0.f, 0.f, 0.f, 0.f};

    __syncthreads();

#pragma unroll
    for (int kblk = 0; kblk < 4; ++kblk) {
        half8 af;
        if constexpr (AFP16) {
            const _Float16* A = (const _Float16*)Xv + (size_t)arowc * 128 + (q << 3);
            af = *(const half8*)(A + kblk * 32);
        } else {
            const float* A = (const float*)Xv + (size_t)arowc * 128 + (q << 3);
            float4 a0 = *(const float4*)(A + kblk * 32);
            float4 a1 = *(const float4*)(A + kblk * 32 + 4);
            af[0] = (_Float16)a0.x; af[1] = (_Float16)a0.y;
            af[2] = (_Float16)a0.z; af[3] = (_Float16)a0.w;
            af[4] = (_Float16)a1.x; af[5] = (_Float16)a1.y;
            af[6] = (_Float16)a1.z; af[7] = (_Float16)a1.w;
        }
#pragma unroll
        for (int nt = 0; nt < NT; ++nt) {
            half8 bf = *(const half8*)&smem[(((nt << 2) + kblk) << 9) + (lane << 3)];
            acc[nt] = __builtin_amdgcn_mfma_f32_16x16x32_f16(af, bf, acc[nt], 0, 0, 0);
        }
    }

    float s[4];
#pragma unroll
    for (int r = 0; r < 4; ++r) {
        int rr = row0 + w * 16 + q * 4 + r;
        s[r] = dinv[rr < N ? rr : N - 1];
    }
    __syncthreads();  // all B reads done before smem reuse
    _Float16* eb = smem;
#pragma unroll
    for (int nt = 0; nt < NT; ++nt)
#pragma unroll
        for (int r = 0; r < 4; ++r)
            eb[(w * 16 + q * 4 + r) * (BN + PAD) + nt * 16 + m] = (_Float16)(acc[nt][r] * s[r]);
    __syncthreads();
    constexpr int CPR = BN / 8;
    for (int i = tid; i < 64 * CPR; i += 256) {
        int row = i / CPR;
        int cf = (i % CPR) * 8;
        if (row0 + row < N)
            *(uint4*)&out[(size_t)(row0 + row) * BN + cf] = *(uint4*)&eb[row * (BN + PAD) + cf];
    }
}

// d=128 aggregation: two nodes per wave; 4 lane-groups of 16; lane loads uint4.
template <bool RELU>
__device__ __forceinline__ void d_agg128(int vb, int tid,
                                         const __half* __restrict__ tp, const int* __restrict__ adj,
                                         const int* __restrict__ startv, const int* __restrict__ deg,
                                         const float* __restrict__ dinv, const float* __restrict__ bias,
                                         _Float16* __restrict__ out, int N) {
    const int n0 = (vb << 3) + ((tid >> 6) << 1);
    const int lane = tid & 63;
    if (n0 >= N) return;   // wave-uniform; no syncs below
    const bool has1 = (n0 + 1) < N;
    const int n1 = has1 ? n0 + 1 : n0;
    const int s0 = startv[n0], s1 = startv[n1];
    const int c0 = deg[n0];
    const int c1 = has1 ? deg[n1] : 0;
    const float one = 1.0f;
    const int g = lane >> 4;
    const int sl = lane & 15;
    const uint4* rowb = (const uint4*)tp;

    float a0[8] = {0.f, 0.f, 0.f, 0.f, 0.f, 0.f, 0.f, 0.f};
    float a1[8] = {0.f, 0.f, 0.f, 0.f, 0.f, 0.f, 0.f, 0.f};
    auto addrow = [&](float* acc, uint4 v) {
        fmix_lo(acc[0], v.x, one); fmix_hi(acc[1], v.x, one);
        fmix_lo(acc[2], v.y, one); fmix_hi(acc[3], v.y, one);
        fmix_lo(acc[4], v.z, one); fmix_hi(acc[5], v.z, one);
        fmix_lo(acc[6], v.w, one); fmix_hi(acc[7], v.w, one);
    };

    {
        uint4 r0 = rowb[(size_t)n0 * 16 + sl];
        uint4 r1 = rowb[(size_t)n1 * 16 + sl];
        if (g == 0) { addrow(a0, r0); if (has1) addrow(a1, r1); }
    }

    int e = 0;
    const int mc = min(c0, c1);
    for (; e + 16 <= mc; e += 16) {
        int j0[4], j1[4];
#pragma unroll
        for (int u = 0; u < 4; ++u) { j0[u] = adj[s0 + e + 4 * u + g]; j1[u] = adj[s1 + e + 4 * u + g]; }
        uint4 v0[4], v1[4];
#pragma unroll
        for (int u = 0; u < 4; ++u) { v0[u] = rowb[(size_t)j0[u] * 16 + sl]; v1[u] = rowb[(size_t)j1[u] * 16 + sl]; }
#pragma unroll
        for (int u = 0; u < 4; ++u) { addrow(a0, v0[u]); addrow(a1, v1[u]); }
    }

    auto finish = [&](float* acc, int s, int cnt, int eS) {
        int ee = eS;
        for (; ee + 16 <= cnt; ee += 16) {
            int j[4];
#pragma unroll
            for (int u = 0; u < 4; ++u) j[u] = adj[s + ee + 4 * u + g];
            uint4 v[4];
#pragma unroll
            for (int u = 0; u < 4; ++u) v[u] = rowb[(size_t)j[u] * 16 + sl];
#pragma unroll
            for (int u = 0; u < 4; ++u) addrow(acc, v[u]);
        }
        if (ee + 8 <= cnt) {
            int j[2];
#pragma unroll
            for (int u = 0; u < 2; ++u) j[u] = adj[s + ee + 4 * u + g];
            uint4 v[2];
#pragma unroll
            for (int u = 0; u < 2; ++u) v[u] = rowb[(size_t)j[u] * 16 + sl];
#pragma unroll
            for (int u = 0; u < 2; ++u) addrow(acc, v[u]);
            ee += 8;
        }
        if (ee + 4 <= cnt) {
            addrow(acc, rowb[(size_t)adj[s + ee + g] * 16 + sl]);
            ee += 4;
        }
        if (ee + g < cnt)
            addrow(acc, rowb[(size_t)adj[s + ee + g] * 16 + sl]);
    };
    finish(a0, s0, c0, e);
    if (has1) finish(a1, s1, c1, e);

#pragma unroll
    for (int i = 0; i < 8; ++i) {
        a0[i] += __shfl_xor(a0[i], 32);
        a0[i] += __shfl_xor(a0[i], 16);
        a1[i] += __shfl_xor(a1[i], 32);
        a1[i] += __shfl_xor(a1[i], 16);
    }
    if (g == 0) {
        float4 b0 = *(const float4*)&bias[sl * 8];
        float4 b1 = *(const float4*)&bias[sl * 8 + 4];
        const float di0 = dinv[n0];
        float o[8];
        o[0] = di0 * a0[0] + b0.x; o[1] = di0 * a0[1] + b0.y;
        o[2] = di0 * a0[2] + b0.z; o[3] = di0 * a0[3] + b0.w;
        o[4] = di0 * a0[4] + b1.x; o[5] = di0 * a0[5] + b1.y;
        o[6] = di0 * a0[6] + b1.z; o[7] = di0 * a0[7] + b1.w;
        if (RELU)
#pragma unroll
            for (int i = 0; i < 8; ++i) o[i] = fmaxf(o[i], 0.f);
        __half2 ov[4];
#pragma unroll
        for (int i = 0; i < 4; ++i) ov[i] = __floats2half2_rn(o[2 * i], o[2 * i + 1]);
        *(uint4*)&out[(size_t)n0 * 128 + sl * 8] = *(uint4*)ov;
        if (has1) {
            const float di1 = dinv[n1];
            o[0] = di1 * a1[0] + b0.x; o[1] = di1 * a1[1] + b0.y;
            o[2] = di1 * a1[2] + b0.z; o[3] = di1 * a1[3] + b0.w;
            o[4] = di1 * a1[4] + b1.x; o[5] = di1 * a1[5] + b1.y;
            o[6] = di1 * a1[6] + b1.z; o[7] = di1 * a1[7] + b1.w;
            if (RELU)
#pragma unroll
                for (int i = 0; i < 8; ++i) o[i] = fmaxf(o[i], 0.f);
#pragma unroll
            for (int i = 0; i < 4; ++i) ov[i] = __floats2half2_rn(o[2 * i], o[2 * i + 1]);
            *(uint4*)&out[(size_t)n1 * 128 + sl * 8] = *(uint4*)ov;
        }
    }
}

__device__ __forceinline__ void d_agg64(int vb, int tid,
                                        const __half* __restrict__ tp, const int* __restrict__ adj,
                                        const int* __restrict__ startv, const int* __restrict__ deg,
                                        const float* __restrict__ dinv, const float* __restrict__ bias,
                                        float* __restrict__ out, int N) {
    const int n0 = (vb << 3) + ((tid >> 6) << 1);
    const int lane = tid & 63;
    if (n0 >= N) return;
    const bool has1 = (n0 + 1) < N;
    const int n1 = has1 ? n0 + 1 : n0;
    const int s0 = startv[n0], s1 = startv[n1];
    const int c0 = deg[n0];
    const int c1 = has1 ? deg[n1] : 0;
    const float one = 1.0f;
    const int g = lane >> 4;
    const int sl = lane & 15;
    const uint2* rowb = (const uint2*)tp;

    float a0[4] = {0.f, 0.f, 0.f, 0.f};
    float a1[4] = {0.f, 0.f, 0.f, 0.f};
    auto addrow = [&](float* acc, uint2 v) {
        fmix_lo(acc[0], v.x, one); fmix_hi(acc[1], v.x, one);
        fmix_lo(acc[2], v.y, one); fmix_hi(acc[3], v.y, one);
    };
    {
        uint2 r0 = rowb[(size_t)n0 * 16 + sl];
        uint2 r1 = rowb[(size_t)n1 * 16 + sl];
        if (g == 0) { addrow(a0, r0); if (has1) addrow(a1, r1); }
    }

    int e = 0;
    const int mc = min(c0, c1);
    for (; e + 16 <= mc; e += 16) {
        int j0[4], j1[4];
#pragma unroll
        for (int u = 0; u < 4; ++u) { j0[u] = adj[s0 + e + 4 * u + g]; j1[u] = adj[s1 + e + 4 * u + g]; }
        uint2 v0[4], v1[4];
#pragma unroll
        for (int u = 0; u < 4; ++u) { v0[u] = rowb[(size_t)j0[u] * 16 + sl]; v1[u] = rowb[(size_t)j1[u] * 16 + sl]; }
#pragma unroll
        for (int u = 0; u < 4; ++u) { addrow(a0, v0[u]); addrow(a1, v1[u]); }
    }

    auto finish = [&](float* acc, int s, int cnt, int eS) {
        int ee = eS;
        for (; ee + 16 <= cnt; ee += 16) {
            int j[4];
#pragma unroll
            for (int u = 0; u < 4; ++u) j[u] = adj[s + ee + 4 * u + g];
            uint2 v[4];
#pragma unroll
            for (int u = 0; u < 4; ++u) v[u] = rowb[(size_t)j[u] * 16 + sl];
#pragma unroll
            for (int u = 0; u < 4; ++u) addrow(acc, v[u]);
        }
        if (ee + 8 <= cnt) {
            int j[2];
#pragma unroll
            for (int u = 0; u < 2; ++u) j[u] = adj[s + ee + 4 * u + g];
            uint2 v[2];
#pragma unroll
            for (int u = 0; u < 2; ++u) v[u] = rowb[(size_t)j[u] * 16 + sl];
#pragma unroll
            for (int u = 0; u < 2; ++u) addrow(acc, v[u]);
            ee += 8;
        }
        if (ee + 4 <= cnt) {
            addrow(acc, rowb[(size_t)adj[s + ee + g] * 16 + sl]);
            ee += 4;
        }
        if (ee + g < cnt)
            addrow(acc, rowb[(size_t)adj[s + ee + g] * 16 + sl]);
    };
    finish(a0, s0, c0, e);
    if (has1) finish(a1, s1, c1, e);

#pragma unroll
    for (int i = 0; i < 4; ++i) {
        a0[i] += __shfl_xor(a0[i], 32);
        a0[i] += __shfl_xor(a0[i], 16);
        a1[i] += __shfl_xor(a1[i], 32);
        a1[i] += __shfl_xor(a1[i], 16);
    }
    if (g == 0) {
        float4 bb = *(const float4*)&bias[sl * 4];
        const float di0 = dinv[n0];
        float4 o;
        o.x = di0 * a0[0] + bb.x; o.y = di0 * a0[1] + bb.y;
        o.z = di0 * a0[2] + bb.z; o.w = di0 * a0[3] + bb.w;
        *(float4*)&out[(size_t)n0 * 64 + sl * 4] = o;
        if (has1) {
            const float di1 = dinv[n1];
            o.x = di1 * a1[0] + bb.x; o.y = di1 * a1[1] + bb.y;
            o.z = di1 * a1[2] + bb.z; o.w = di1 * a1[3] + bb.w;
            *(float4*)&out[(size_t)n1 * 64 + sl * 4] = o;
        }
    }
}

// ---------------- mega cooperative kernel: whole 3-layer GCN, 1 dispatch, 7 sw barriers
__global__ void __launch_bounds__(256, 4)
k_mega(const float* x, const int* src, const int* dst,
       const float* W1, const float* W2, const float* W3,
       const float* b1, const float* b2, const float* b3,
       float* out, __half* tp, _Float16* hbuf,
       int* deg, float* dinv, int* stv, int* bcur, int* adj,
       _Float16* wz1, _Float16* wz2, _Float16* wz3, int* bar) {
    __shared__ __align__(16) _Float16 smem[128 * 128];   // 32 KB union for all phases
    int* ilds = (int*)smem;
    const int tid = threadIdx.x;
    const int nb = gridDim.x;
    int* ebuf = (int*)tp;   // alias: tp not live until gemm1

    // PH0: weight swizzles (independent) + edge partition (bcur pre-zeroed by memset)
    {
        const int gid = blockIdx.x * 256 + tid;
        for (int t = gid; t < 5120; t += nb * 256)
            wswz_one(t, W1, W2, W3, wz1, wz2, wz3);
    }
    for (int vb = blockIdx.x; vb < 256; vb += nb)
        d_part(vb, tid, ilds, ilds + 200, src, dst, bcur, ebuf, N_EDGES);
    gbar(bar + 0, nb);
    // PH1: per-bucket counting sort
    for (int vb = blockIdx.x; vb < NBUCKET; vb += nb)
        d_bsort(vb, tid, ilds, ilds + 512, ebuf, bcur, adj, stv, deg, dinv, N_NODES);
    gbar(bar + 1, nb);
    // PH2..PH7: three (gemm, agg) layer pairs
    for (int vb = blockIdx.x; vb < VB_GEMM; vb += nb)
        d_gemm<128, false>(vb, tid, smem, x, wz1, dinv, tp, N_NODES);
    gbar(bar + 2, nb);
    for (int vb = blockIdx.x; vb < VB_AGG; vb += nb)
        d_agg128<true>(vb, tid, tp, adj, stv, deg, dinv, b1, hbuf, N_NODES);
    gbar(bar + 3, nb);
    for (int vb = blockIdx.x; vb < VB_GEMM; vb += nb)
        d_gemm<128, true>(vb, tid, smem, hbuf, wz2, dinv, tp, N_NODES);
    gbar(bar + 4, nb);
    for (int vb = blockIdx.x; vb < VB_AGG; vb += nb)
        d_agg128<true>(vb, tid, tp, adj, stv, deg, dinv, b2, hbuf, N_NODES);
    gbar(bar + 5, nb);
    for (int vb = blockIdx.x; vb < VB_GEMM; vb += nb)
        d_gemm<64, true>(vb, tid, smem, hbuf, wz3, dinv, tp, N_NODES);
    gbar(bar + 6, nb);
    for (int vb = blockIdx.x; vb < VB_AGG; vb += nb)
        d_agg64(vb, tid, (const __half*)tp, adj, stv, deg, dinv, b3, out, N_NODES);
}

// ---------------- fallback wrappers (round-2 structure), used if coop launch unsupported
__launch_bounds__(256)
__global__ void k_part_wswz(const int* __restrict__ src, const int* __restrict__ dst,
                            int* __restrict__ bcur, int* __restrict__ ebuf, int E,
                            const float* __restrict__ W1, const float* __restrict__ W2,
                            const float* __restrict__ W3, _Float16* __restrict__ wz1,
                            _Float16* __restrict__ wz2, _Float16* __restrict__ wz3) {
    __shared__ int hb[400];
    if (blockIdx.x >= 256) {
        int t = (blockIdx.x - 256) * 256 + threadIdx.x;
        if (t < 5120) wswz_one(t, W1, W2, W3, wz1, wz2, wz3);
        return;
    }
    d_part(blockIdx.x, threadIdx.x, hb, hb + 200, src, dst, bcur, ebuf, E);
}

__launch_bounds__(256)
__global__ void k_bsort(const int* __restrict__ ebuf, const int* __restrict__ bcur,
                        int* __restrict__ adj, int* __restrict__ stv,
                        int* __restrict__ deg, float* __restrict__ dinv, int N) {
    __shared__ int cb[1024];
    d_bsort(blockIdx.x, threadIdx.x, cb, cb + 512, ebuf, bcur, adj, stv, deg, dinv, N);
}

template <int BN, bool AFP16>
__launch_bounds__(256, 4)
__global__ void k_gemm_mfma(const void* __restrict__ Xv, const _Float16* __restrict__ wsz,
                            const float* __restrict__ dinv, __half* __restrict__ out, int N) {
    __shared__ __align__(16) _Float16 smem[BN * 128];
    d_gemm<BN, AFP16>(blockIdx.x, threadIdx.x, smem, Xv, wsz, dinv, out, N);
}

template <bool RELU>
__launch_bounds__(256)
__global__ void k_agg128(const __half* __restrict__ tp, const int* __restrict__ adj,
                         const int* __restrict__ startv, const int* __restrict__ deg,
                         const float* __restrict__ dinv, const float* __restrict__ bias,
                         _Float16* __restrict__ out, int N) {
    d_agg128<RELU>(blockIdx.x, threadIdx.x, tp, adj, startv, deg, dinv, bias, out, N);
}

__launch_bounds__(256)
__global__ void k_agg64(const __half* __restrict__ tp, const int* __restrict__ adj,
                        const int* __restrict__ startv, const int* __restrict__ deg,
                        const float* __restrict__ dinv, const float* __restrict__ bias,
                        float* __restrict__ out, int N) {
    d_agg64(blockIdx.x, threadIdx.x, tp, adj, startv, deg, dinv, bias, out, N);
}

extern "C" void kernel_launch(void* const* d_in, const int* in_sizes, int n_in,
                              void* d_out, int out_size, void* d_ws, size_t ws_size,
                              hipStream_t stream) {
    const float* x  = (const float*)d_in[0];
    const int*   ei = (const int*)d_in[1];
    const float* W1 = (const float*)d_in[2];
    const float* b1 = (const float*)d_in[3];
    const float* W2 = (const float*)d_in[4];
    const float* b2 = (const float*)d_in[5];
    const float* W3 = (const float*)d_in[6];
    const float* b3 = (const float*)d_in[7];
    float* out = (float*)d_out;
    const int* src = ei;            // edge_index[0]
    const int* dst = ei + N_EDGES;  // edge_index[1]

    char* p = (char*)d_ws;
    __half* tp      = (__half*)p;    p += (size_t)N_NODES * 128 * 2;   // 25.6 MB
    _Float16* hbuf  = (_Float16*)p;  p += (size_t)N_NODES * 128 * 2;   // 25.6 MB
    int*   deg  = (int*)p;    p += (size_t)N_NODES * 4;
    float* dinv = (float*)p;  p += (size_t)N_NODES * 4;
    int*   stv  = (int*)p;    p += (size_t)N_NODES * 4;
    int*   bCur = (int*)p;    p += 1024;                               // bucket fill counts
    int*   bar  = (int*)p;    p += 64;                                 // 7 barrier counters
    int*   adj  = (int*)p;    p += (size_t)NBUCKET * CAP * 4 + 16384;  // 7.0 MB bucketed
    _Float16* wz1 = (_Float16*)p; p += 16384 * 2;                      // 32 KB
    _Float16* wz2 = (_Float16*)p; p += 16384 * 2;                      // 32 KB
    _Float16* wz3 = (_Float16*)p; p += 8192 * 2;                       // 16 KB
    size_t need = (size_t)(p - (char*)d_ws);
    if (ws_size < need) return;  // visible failure rather than OOB

    int* ebuf = (int*)tp;  // 7.0 MB alias; tp not live until layer-1 GEMM

    // zero bucket cursors + barrier counters (contiguous region)
    hipMemsetAsync(bCur, 0, 1024 + 64, stream);

    // ---- preferred path: single cooperative dispatch with our own barrier
    int maxb = 0;
    hipError_t oe = hipOccupancyMaxActiveBlocksPerMultiprocessor(&maxb, k_mega, 256, 0);
    int nblocks = (oe == hipSuccess && maxb > 0) ? min(1024, maxb * 256) : 0;
    hipError_t cerr = hipErrorUnknown;
    if (nblocks > 0) {
        void* kargs[] = {(void*)&x, (void*)&src, (void*)&dst,
                         (void*)&W1, (void*)&W2, (void*)&W3,
                         (void*)&b1, (void*)&b2, (void*)&b3,
                         (void*)&out, (void*)&tp, (void*)&hbuf,
                         (void*)&deg, (void*)&dinv, (void*)&stv,
                         (void*)&bCur, (void*)&adj,
                         (void*)&wz1, (void*)&wz2, (void*)&wz3, (void*)&bar};
        cerr = hipLaunchCooperativeKernel((const void*)k_mega, dim3(nblocks), dim3(256),
                                          kargs, 0, stream);
    }
    if (cerr == hipSuccess) return;

    // ---- fallback: classic 9-dispatch pipeline (round-2, 355 us)
    k_part_wswz<<<276, 256, 0, stream>>>(src, dst, bCur, ebuf, N_EDGES,
                                         W1, W2, W3, wz1, wz2, wz3);
    k_bsort<<<NBUCKET, 256, 0, stream>>>(ebuf, bCur, adj, stv, deg, dinv, N_NODES);

    const int gb = VB_GEMM;
    const int ab = VB_AGG;
    k_gemm_mfma<128, false><<<gb, 256, 0, stream>>>(x, wz1, dinv, tp, N_NODES);
    k_agg128<true><<<ab, 256, 0, stream>>>(tp, adj, stv, deg, dinv, b1, hbuf, N_NODES);
    k_gemm_mfma<128, true><<<gb, 256, 0, stream>>>(hbuf, wz2, dinv, tp, N_NODES);
    k_agg128<true><<<ab, 256, 0, stream>>>(tp, adj, stv, deg, dinv, b2, hbuf, N_NODES);
    k_gemm_mfma<64, true><<<gb, 256, 0, stream>>>(hbuf, wz3, dinv, tp, N_NODES);
    k_agg64<<<ab, 256, 0, stream>>>(tp, adj, stv, deg, dinv, b3, out, N_NODES);
}

// Round 6
// 357.449 us; speedup vs baseline: 4.7218x; 4.7218x over previous
//
#include <hip/hip_runtime.h>
#include <hip/hip_fp16.h>

#define N_NODES 100000
#define N_EDGES 1600000
#define NBUCKET 196          // ceil(100000 / 512)
#define CAP     8960         // per-bucket capacity: mean 8163, sigma 90 -> +8.8 sigma
#define EPB     6250         // edges per block in partition (256 blocks)

typedef _Float16 half8 __attribute__((ext_vector_type(8)));
typedef float float4v __attribute__((ext_vector_type(4)));

// acc += (float)lo_half(w)  /  acc += (float)hi_half(w)  in ONE VALU op each.
// v_fma_mix_f32: numerically identical to cvt+add (h exact in f32, x1.0 exact).
__device__ __forceinline__ void fmix_lo(float& a, unsigned int w, float one) {
    asm("v_fma_mix_f32 %0, %1, %2, %0 op_sel:[0,0,0] op_sel_hi:[1,0,0]"
        : "+v"(a) : "v"(w), "v"(one));
}
__device__ __forceinline__ void fmix_hi(float& a, unsigned int w, float one) {
    asm("v_fma_mix_f32 %0, %1, %2, %0 op_sel:[1,0,0] op_sel_hi:[1,0,0]"
        : "+v"(a) : "v"(w), "v"(one));
}

// ---------------- partition edges into fixed-capacity bucket segments
// packed entry: (src << 9) | (dst & 511)  [src < 2^17, bucket-local dst < 2^9]
// Blocks 256..275 instead perform the W->fp16 B-fragment swizzles (fused k_wswz).
__launch_bounds__(256)
__global__ void k_part_wswz(const int* __restrict__ src, const int* __restrict__ dst,
                            int* __restrict__ bcur, int* __restrict__ ebuf, int E,
                            const float* __restrict__ W1, const float* __restrict__ W2,
                            const float* __restrict__ W3, _Float16* __restrict__ wz1,
                            _Float16* __restrict__ wz2, _Float16* __restrict__ wz3) {
    if (blockIdx.x >= 256) {
        // -------- weight swizzle path (20 blocks * 256 = 5120 threads)
        int t = (blockIdx.x - 256) * 256 + threadIdx.x;
        const float* W; _Float16* wsz; int BN;
        if (t < 2048)      { W = W1; wsz = wz1; BN = 128; }
        else if (t < 4096) { W = W2; wsz = wz2; BN = 128; t -= 2048; }
        else if (t < 5120) { W = W3; wsz = wz3; BN = 64;  t -= 4096; }
        else return;
        const int l = t & 63;
        const int kblk = (t >> 6) & 3;
        const int nt = t >> 8;
        const int krow = kblk * 32 + ((l >> 4) << 3);
        const int col = nt * 16 + (l & 15);
        _Float16 v[8];
#pragma unroll
        for (int j = 0; j < 8; ++j) v[j] = (_Float16)W[(krow + j) * BN + col];
        *(uint4*)&wsz[t << 3] = *(uint4*)v;
        return;
    }
    __shared__ int hist[200];
    __shared__ int basebkt[200];
    const int tid = threadIdx.x;
    if (tid < 200) hist[tid] = 0;
    __syncthreads();
    const int e0 = blockIdx.x * EPB, e1 = min(e0 + EPB, E);
    for (int e = e0 + tid; e < e1; e += 256) atomicAdd(&hist[dst[e] >> 9], 1);
    __syncthreads();
    if (tid < NBUCKET) {
        int h = hist[tid];
        basebkt[tid] = tid * CAP + (h ? atomicAdd(&bcur[tid], h) : 0);
    }
    __syncthreads();
    if (tid < 200) hist[tid] = 0;
    __syncthreads();
    for (int e = e0 + tid; e < e1; e += 256) {
        int d = dst[e];
        int bk = d >> 9;
        int o = atomicAdd(&hist[bk], 1);
        ebuf[basebkt[bk] + o] = (src[e] << 9) | (d & 511);
    }
}

// ---------------- per-bucket counting sort -> deg, stv, dinv, adj (bucketed layout)
__launch_bounds__(256)
__global__ void k_bsort(const int* __restrict__ ebuf, const int* __restrict__ bcur,
                        int* __restrict__ adj, int* __restrict__ stv,
                        int* __restrict__ deg, float* __restrict__ dinv, int N) {
    __shared__ int cnt[512];
    __shared__ int offs[512];
    const int b = blockIdx.x;
    const int tid = threadIdx.x;
    const int base = b * CAP;
    const int n_b = min(bcur[b], CAP);
    const int node0 = b << 9;
    cnt[tid] = 0; cnt[tid + 256] = 0;
    __syncthreads();
    for (int i = tid; i < n_b; i += 256)
        atomicAdd(&cnt[ebuf[base + i] & 511], 1);
    __syncthreads();
    if (tid < 64) {  // wave-0 exclusive scan of 512
        int v[8], tot = 0;
#pragma unroll
        for (int j = 0; j < 8; ++j) { int t = cnt[tid * 8 + j]; v[j] = tot; tot += t; }
        int inc = tot;
#pragma unroll
        for (int d = 1; d < 64; d <<= 1) {
            int u = __shfl_up(inc, d, 64);
            if (tid >= d) inc += u;
        }
        const int excl = inc - tot;
#pragma unroll
        for (int j = 0; j < 8; ++j) offs[tid * 8 + j] = excl + v[j];
    }
    __syncthreads();
#pragma unroll
    for (int h = 0; h < 2; ++h) {
        int local = tid + h * 256;
        int node = node0 + local;
        if (node < N) {
            stv[node] = base + offs[local];
            deg[node] = cnt[local];
            dinv[node] = rsqrtf((float)(cnt[local] + 1));
        }
    }
    __syncthreads();
    for (int i = tid; i < n_b; i += 256) {  // offs doubles as cursor
        int pk = ebuf[base + i];
        int pos = atomicAdd(&offs[pk & 511], 1);
        adj[base + pos] = pk >> 9;
    }
}

// ---------------- MFMA GEMM: tp[i][:] = fp16( dinv[i] * (X[i][:] @ W) ), K=128
template <int BN, bool AFP16>
__launch_bounds__(256, 4)
__global__ void k_gemm_mfma(const void* __restrict__ Xv, const _Float16* __restrict__ wsz,
                            const float* __restrict__ dinv, __half* __restrict__ out, int N) {
    constexpr int NT = BN / 16;
    constexpr int PAD = 8;
    __shared__ __align__(16) _Float16 smem[BN * 128];  // B frags; reused for epilogue

    const int tid = threadIdx.x;
    for (int i = tid; i < BN * 16; i += 256)
        *(uint4*)&smem[i << 3] = *(const uint4*)&wsz[i << 3];

    const int w = tid >> 6;
    const int lane = tid & 63;
    const int q = lane >> 4;
    const int m = lane & 15;
    const int row0 = blockIdx.x * 64;
    const int arow = row0 + w * 16 + m;
    const int arowc = arow < N ? arow : N - 1;

    float4v acc[NT];
#pragma unroll
    for (int nt = 0; nt < NT; ++nt) acc[nt] = (float4v){0.f, 0.f, 0.f, 0.f};

    __syncthreads();

#pragma unroll
    for (int kblk = 0; kblk < 4; ++kblk) {
        half8 af;
        if constexpr (AFP16) {
            const _Float16* A = (const _Float16*)Xv + (size_t)arowc * 128 + (q << 3);
            af = *(const half8*)(A + kblk * 32);
        } else {
            const float* A = (const float*)Xv + (size_t)arowc * 128 + (q << 3);
            float4 a0 = *(const float4*)(A + kblk * 32);
            float4 a1 = *(const float4*)(A + kblk * 32 + 4);
            af[0] = (_Float16)a0.x; af[1] = (_Float16)a0.y;
            af[2] = (_Float16)a0.z; af[3] = (_Float16)a0.w;
            af[4] = (_Float16)a1.x; af[5] = (_Float16)a1.y;
            af[6] = (_Float16)a1.z; af[7] = (_Float16)a1.w;
        }
#pragma unroll
        for (int nt = 0; nt < NT; ++nt) {
            half8 bf = *(const half8*)&smem[(((nt << 2) + kblk) << 9) + (lane << 3)];
            acc[nt] = __builtin_amdgcn_mfma_f32_16x16x32_f16(af, bf, acc[nt], 0, 0, 0);
        }
    }

    float s[4];
#pragma unroll
    for (int r = 0; r < 4; ++r) {
        int rr = row0 + w * 16 + q * 4 + r;
        s[r] = dinv[rr < N ? rr : N - 1];
    }
    __syncthreads();  // all B reads done before smem reuse
    _Float16* eb = smem;
#pragma unroll
    for (int nt = 0; nt < NT; ++nt)
#pragma unroll
        for (int r = 0; r < 4; ++r)
            eb[(w * 16 + q * 4 + r) * (BN + PAD) + nt * 16 + m] = (_Float16)(acc[nt][r] * s[r]);
    __syncthreads();
    constexpr int CPR = BN / 8;
    for (int i = tid; i < 64 * CPR; i += 256) {
        int row = i / CPR;
        int cf = (i % CPR) * 8;
        if (row0 + row < N)
            *(uint4*)&out[(size_t)(row0 + row) * BN + cf] = *(uint4*)&eb[row * (BN + PAD) + cf];
    }
}

// ---------------- d=128 aggregation: TWO nodes per wave for 2x miss-level parallelism
// 4 groups of 16 lanes; group g handles edge e+g of each node; lane loads uint4 (8 cols).
template <bool RELU>
__launch_bounds__(256)
__global__ void k_agg128(const __half* __restrict__ tp, const int* __restrict__ adj,
                         const int* __restrict__ startv, const int* __restrict__ deg,
                         const float* __restrict__ dinv, const float* __restrict__ bias,
                         _Float16* __restrict__ out, int N) {
    const int n0 = (blockIdx.x << 3) + ((threadIdx.x >> 6) << 1);
    const int lane = threadIdx.x & 63;
    if (n0 >= N) return;
    const bool has1 = (n0 + 1) < N;
    const int n1 = has1 ? n0 + 1 : n0;
    const int s0 = startv[n0], s1 = startv[n1];
    const int c0 = deg[n0];
    const int c1 = has1 ? deg[n1] : 0;
    const float one = 1.0f;
    const int g = lane >> 4;        // edge group 0..3
    const int sl = lane & 15;       // 16 B chunk within row
    const uint4* rowb = (const uint4*)tp;   // row stride = 16 uint4 (256 B)

    float a0[8] = {0.f, 0.f, 0.f, 0.f, 0.f, 0.f, 0.f, 0.f};
    float a1[8] = {0.f, 0.f, 0.f, 0.f, 0.f, 0.f, 0.f, 0.f};
    auto addrow = [&](float* acc, uint4 v) {
        fmix_lo(acc[0], v.x, one); fmix_hi(acc[1], v.x, one);
        fmix_lo(acc[2], v.y, one); fmix_hi(acc[3], v.y, one);
        fmix_lo(acc[4], v.z, one); fmix_hi(acc[5], v.z, one);
        fmix_lo(acc[6], v.w, one); fmix_hi(acc[7], v.w, one);
    };

    // self-loops: both rows in flight together
    {
        uint4 r0 = rowb[(size_t)n0 * 16 + sl];
        uint4 r1 = rowb[(size_t)n1 * 16 + sl];
        if (g == 0) { addrow(a0, r0); if (has1) addrow(a1, r1); }
    }

    // joint main loop: 8 row-gathers in flight per lane
    int e = 0;
    const int mc = min(c0, c1);
    for (; e + 16 <= mc; e += 16) {
        int j0[4], j1[4];
#pragma unroll
        for (int u = 0; u < 4; ++u) { j0[u] = adj[s0 + e + 4 * u + g]; j1[u] = adj[s1 + e + 4 * u + g]; }
        uint4 v0[4], v1[4];
#pragma unroll
        for (int u = 0; u < 4; ++u) { v0[u] = rowb[(size_t)j0[u] * 16 + sl]; v1[u] = rowb[(size_t)j1[u] * 16 + sl]; }
#pragma unroll
        for (int u = 0; u < 4; ++u) { addrow(a0, v0[u]); addrow(a1, v1[u]); }
    }

    // per-node finish ladder (branches are wave-uniform)
    auto finish = [&](float* acc, int s, int cnt, int eS) {
        int ee = eS;
        for (; ee + 16 <= cnt; ee += 16) {
            int j[4];
#pragma unroll
            for (int u = 0; u < 4; ++u) j[u] = adj[s + ee + 4 * u + g];
            uint4 v[4];
#pragma unroll
            for (int u = 0; u < 4; ++u) v[u] = rowb[(size_t)j[u] * 16 + sl];
#pragma unroll
            for (int u = 0; u < 4; ++u) addrow(acc, v[u]);
        }
        if (ee + 8 <= cnt) {
            int j[2];
#pragma unroll
            for (int u = 0; u < 2; ++u) j[u] = adj[s + ee + 4 * u + g];
            uint4 v[2];
#pragma unroll
            for (int u = 0; u < 2; ++u) v[u] = rowb[(size_t)j[u] * 16 + sl];
#pragma unroll
            for (int u = 0; u < 2; ++u) addrow(acc, v[u]);
            ee += 8;
        }
        if (ee + 4 <= cnt) {
            addrow(acc, rowb[(size_t)adj[s + ee + g] * 16 + sl]);
            ee += 4;
        }
        if (ee + g < cnt)
            addrow(acc, rowb[(size_t)adj[s + ee + g] * 16 + sl]);
    };
    finish(a0, s0, c0, e);
    if (has1) finish(a1, s1, c1, e);

#pragma unroll
    for (int i = 0; i < 8; ++i) {
        a0[i] += __shfl_xor(a0[i], 32);
        a0[i] += __shfl_xor(a0[i], 16);
        a1[i] += __shfl_xor(a1[i], 32);
        a1[i] += __shfl_xor(a1[i], 16);
    }
    if (g == 0) {
        float4 b0 = *(const float4*)&bias[sl * 8];
        float4 b1 = *(const float4*)&bias[sl * 8 + 4];
        const float di0 = dinv[n0];
        float o[8];
        o[0] = di0 * a0[0] + b0.x; o[1] = di0 * a0[1] + b0.y;
        o[2] = di0 * a0[2] + b0.z; o[3] = di0 * a0[3] + b0.w;
        o[4] = di0 * a0[4] + b1.x; o[5] = di0 * a0[5] + b1.y;
        o[6] = di0 * a0[6] + b1.z; o[7] = di0 * a0[7] + b1.w;
        if (RELU)
#pragma unroll
            for (int i = 0; i < 8; ++i) o[i] = fmaxf(o[i], 0.f);
        __half2 ov[4];
#pragma unroll
        for (int i = 0; i < 4; ++i) ov[i] = __floats2half2_rn(o[2 * i], o[2 * i + 1]);
        *(uint4*)&out[(size_t)n0 * 128 + sl * 8] = *(uint4*)ov;
        if (has1) {
            const float di1 = dinv[n1];
            o[0] = di1 * a1[0] + b0.x; o[1] = di1 * a1[1] + b0.y;
            o[2] = di1 * a1[2] + b0.z; o[3] = di1 * a1[3] + b0.w;
            o[4] = di1 * a1[4] + b1.x; o[5] = di1 * a1[5] + b1.y;
            o[6] = di1 * a1[6] + b1.z; o[7] = di1 * a1[7] + b1.w;
            if (RELU)
#pragma unroll
                for (int i = 0; i < 8; ++i) o[i] = fmaxf(o[i], 0.f);
#pragma unroll
            for (int i = 0; i < 4; ++i) ov[i] = __floats2half2_rn(o[2 * i], o[2 * i + 1]);
            *(uint4*)&out[(size_t)n1 * 128 + sl * 8] = *(uint4*)ov;
        }
    }
}

// ---------------- d=64 aggregation (fp32 out): TWO nodes per wave
__launch_bounds__(256)
__global__ void k_agg64(const __half* __restrict__ tp, const int* __restrict__ adj,
                        const int* __restrict__ startv, const int* __restrict__ deg,
                        const float* __restrict__ dinv, const float* __restrict__ bias,
                        float* __restrict__ out, int N) {
    const int n0 = (blockIdx.x << 3) + ((threadIdx.x >> 6) << 1);
    const int lane = threadIdx.x & 63;
    if (n0 >= N) return;
    const bool has1 = (n0 + 1) < N;
    const int n1 = has1 ? n0 + 1 : n0;
    const int s0 = startv[n0], s1 = startv[n1];
    const int c0 = deg[n0];
    const int c1 = has1 ? deg[n1] : 0;
    const float one = 1.0f;
    const int g = lane >> 4;
    const int sl = lane & 15;
    const uint2* rowb = (const uint2*)tp;   // row stride = 16 uint2 (128 B)

    float a0[4] = {0.f, 0.f, 0.f, 0.f};
    float a1[4] = {0.f, 0.f, 0.f, 0.f};
    auto addrow = [&](float* acc, uint2 v) {
        fmix_lo(acc[0], v.x, one); fmix_hi(acc[1], v.x, one);
        fmix_lo(acc[2], v.y, one); fmix_hi(acc[3], v.y, one);
    };
    {
        uint2 r0 = rowb[(size_t)n0 * 16 + sl];
        uint2 r1 = rowb[(size_t)n1 * 16 + sl];
        if (g == 0) { addrow(a0, r0); if (has1) addrow(a1, r1); }
    }

    int e = 0;
    const int mc = min(c0, c1);
    for (; e + 16 <= mc; e += 16) {
        int j0[4], j1[4];
#pragma unroll
        for (int u = 0; u < 4; ++u) { j0[u] = adj[s0 + e + 4 * u + g]; j1[u] = adj[s1 + e + 4 * u + g]; }
        uint2 v0[4], v1[4];
#pragma unroll
        for (int u = 0; u < 4; ++u) { v0[u] = rowb[(size_t)j0[u] * 16 + sl]; v1[u] = rowb[(size_t)j1[u] * 16 + sl]; }
#pragma unroll
        for (int u = 0; u < 4; ++u) { addrow(a0, v0[u]); addrow(a1, v1[u]); }
    }

    auto finish = [&](float* acc, int s, int cnt, int eS) {
        int ee = eS;
        for (; ee + 16 <= cnt; ee += 16) {
            int j[4];
#pragma unroll
            for (int u = 0; u < 4; ++u) j[u] = adj[s + ee + 4 * u + g];
            uint2 v[4];
#pragma unroll
            for (int u = 0; u < 4; ++u) v[u] = rowb[(size_t)j[u] * 16 + sl];
#pragma unroll
            for (int u = 0; u < 4; ++u) addrow(acc, v[u]);
        }
        if (ee + 8 <= cnt) {
            int j[2];
#pragma unroll
            for (int u = 0; u < 2; ++u) j[u] = adj[s + ee + 4 * u + g];
            uint2 v[2];
#pragma unroll
            for (int u = 0; u < 2; ++u) v[u] = rowb[(size_t)j[u] * 16 + sl];
#pragma unroll
            for (int u = 0; u < 2; ++u) addrow(acc, v[u]);
            ee += 8;
        }
        if (ee + 4 <= cnt) {
            addrow(acc, rowb[(size_t)adj[s + ee + g] * 16 + sl]);
            ee += 4;
        }
        if (ee + g < cnt)
            addrow(acc, rowb[(size_t)adj[s + ee + g] * 16 + sl]);
    };
    finish(a0, s0, c0, e);
    if (has1) finish(a1, s1, c1, e);

#pragma unroll
    for (int i = 0; i < 4; ++i) {
        a0[i] += __shfl_xor(a0[i], 32);
        a0[i] += __shfl_xor(a0[i], 16);
        a1[i] += __shfl_xor(a1[i], 32);
        a1[i] += __shfl_xor(a1[i], 16);
    }
    if (g == 0) {
        float4 bb = *(const float4*)&bias[sl * 4];
        const float di0 = dinv[n0];
        float4 o;
        o.x = di0 * a0[0] + bb.x; o.y = di0 * a0[1] + bb.y;
        o.z = di0 * a0[2] + bb.z; o.w = di0 * a0[3] + bb.w;
        *(float4*)&out[(size_t)n0 * 64 + sl * 4] = o;
        if (has1) {
            const float di1 = dinv[n1];
            o.x = di1 * a1[0] + bb.x; o.y = di1 * a1[1] + bb.y;
            o.z = di1 * a1[2] + bb.z; o.w = di1 * a1[3] + bb.w;
            *(float4*)&out[(size_t)n1 * 64 + sl * 4] = o;
        }
    }
}

extern "C" void kernel_launch(void* const* d_in, const int* in_sizes, int n_in,
                              void* d_out, int out_size, void* d_ws, size_t ws_size,
                              hipStream_t stream) {
    const float* x  = (const float*)d_in[0];
    const int*   ei = (const int*)d_in[1];
    const float* W1 = (const float*)d_in[2];
    const float* b1 = (const float*)d_in[3];
    const float* W2 = (const float*)d_in[4];
    const float* b2 = (const float*)d_in[5];
    const float* W3 = (const float*)d_in[6];
    const float* b3 = (const float*)d_in[7];
    float* out = (float*)d_out;
    const int* src = ei;            // edge_index[0]
    const int* dst = ei + N_EDGES;  // edge_index[1]

    char* p = (char*)d_ws;
    __half* tp      = (__half*)p;    p += (size_t)N_NODES * 128 * 2;   // 25.6 MB
    _Float16* hbuf  = (_Float16*)p;  p += (size_t)N_NODES * 128 * 2;   // 25.6 MB
    int*   deg  = (int*)p;    p += (size_t)N_NODES * 4;
    float* dinv = (float*)p;  p += (size_t)N_NODES * 4;
    int*   stv  = (int*)p;    p += (size_t)N_NODES * 4;
    int*   bCur = (int*)p;    p += 1024;                               // bucket fill counts
    int*   adj  = (int*)p;    p += (size_t)NBUCKET * CAP * 4 + 16384;  // 7.0 MB bucketed
    _Float16* wz1 = (_Float16*)p; p += 16384 * 2;                      // 32 KB
    _Float16* wz2 = (_Float16*)p; p += 16384 * 2;                      // 32 KB
    _Float16* wz3 = (_Float16*)p; p += 8192 * 2;                       // 16 KB
    size_t need = (size_t)(p - (char*)d_ws);
    if (ws_size < need) return;  // visible failure rather than OOB

    int* ebuf = (int*)tp;  // 7.0 MB alias; tp not live until layer-1 GEMM

    hipMemsetAsync(bCur, 0, 1024, stream);
    k_part_wswz<<<276, 256, 0, stream>>>(src, dst, bCur, ebuf, N_EDGES,
                                         W1, W2, W3, wz1, wz2, wz3);
    k_bsort<<<NBUCKET, 256, 0, stream>>>(ebuf, bCur, adj, stv, deg, dinv, N_NODES);

    const int gb = (N_NODES + 63) / 64;
    const int ab = (N_NODES + 7) / 8;
    // layer 1: relu(agg(x@W1) + b1) -> fp16 hbuf
    k_gemm_mfma<128, false><<<gb, 256, 0, stream>>>(x, wz1, dinv, tp, N_NODES);
    k_agg128<true><<<ab, 256, 0, stream>>>(tp, adj, stv, deg, dinv, b1, hbuf, N_NODES);
    // layer 2
    k_gemm_mfma<128, true><<<gb, 256, 0, stream>>>(hbuf, wz2, dinv, tp, N_NODES);
    k_agg128<true><<<ab, 256, 0, stream>>>(tp, adj, stv, deg, dinv, b2, hbuf, N_NODES);
    // layer 3: agg(h@W3) + b3 (no relu) -> fp32 out
    k_gemm_mfma<64, true><<<gb, 256, 0, stream>>>(hbuf, wz3, dinv, tp, N_NODES);
    k_agg64<<<ab, 256, 0, stream>>>(tp, adj, stv, deg, dinv, b3, out, N_NODES);
}

// Round 7
// 354.014 us; speedup vs baseline: 4.7676x; 1.0097x over previous
//
#include <hip/hip_runtime.h>
#include <hip/hip_fp16.h>

#define N_NODES 100000
#define N_EDGES 1600000
#define NBUCKET 196          // ceil(100000 / 512)
#define CAP     8960         // per-bucket capacity: mean 8163, sigma 90 -> +8.8 sigma
#define EPB     6250         // edges per block in partition (256 blocks)

typedef _Float16 half8 __attribute__((ext_vector_type(8)));
typedef float float4v __attribute__((ext_vector_type(4)));

// acc += (float)lo_half(w)  /  acc += (float)hi_half(w)  in ONE VALU op each.
// v_fma_mix_f32: numerically identical to cvt+add (h exact in f32, x1.0 exact).
__device__ __forceinline__ void fmix_lo(float& a, unsigned int w, float one) {
    asm("v_fma_mix_f32 %0, %1, %2, %0 op_sel:[0,0,0] op_sel_hi:[1,0,0]"
        : "+v"(a) : "v"(w), "v"(one));
}
__device__ __forceinline__ void fmix_hi(float& a, unsigned int w, float one) {
    asm("v_fma_mix_f32 %0, %1, %2, %0 op_sel:[1,0,0] op_sel_hi:[1,0,0]"
        : "+v"(a) : "v"(w), "v"(one));
}

// ---------------- partition edges into fixed-capacity bucket segments
// packed entry: (src << 9) | (dst & 511)  [src < 2^17, bucket-local dst < 2^9]
// Blocks 256..275 instead perform the W->fp16 B-fragment swizzles (fused k_wswz).
__launch_bounds__(256)
__global__ void k_part_wswz(const int* __restrict__ src, const int* __restrict__ dst,
                            int* __restrict__ bcur, int* __restrict__ ebuf, int E,
                            const float* __restrict__ W1, const float* __restrict__ W2,
                            const float* __restrict__ W3, _Float16* __restrict__ wz1,
                            _Float16* __restrict__ wz2, _Float16* __restrict__ wz3) {
    if (blockIdx.x >= 256) {
        // -------- weight swizzle path (20 blocks * 256 = 5120 threads)
        int t = (blockIdx.x - 256) * 256 + threadIdx.x;
        const float* W; _Float16* wsz; int BN;
        if (t < 2048)      { W = W1; wsz = wz1; BN = 128; }
        else if (t < 4096) { W = W2; wsz = wz2; BN = 128; t -= 2048; }
        else if (t < 5120) { W = W3; wsz = wz3; BN = 64;  t -= 4096; }
        else return;
        const int l = t & 63;
        const int kblk = (t >> 6) & 3;
        const int nt = t >> 8;
        const int krow = kblk * 32 + ((l >> 4) << 3);
        const int col = nt * 16 + (l & 15);
        _Float16 v[8];
#pragma unroll
        for (int j = 0; j < 8; ++j) v[j] = (_Float16)W[(krow + j) * BN + col];
        *(uint4*)&wsz[t << 3] = *(uint4*)v;
        return;
    }
    __shared__ int hist[200];
    __shared__ int basebkt[200];
    const int tid = threadIdx.x;
    if (tid < 200) hist[tid] = 0;
    __syncthreads();
    const int e0 = blockIdx.x * EPB, e1 = min(e0 + EPB, E);
    for (int e = e0 + tid; e < e1; e += 256) atomicAdd(&hist[dst[e] >> 9], 1);
    __syncthreads();
    if (tid < NBUCKET) {
        int h = hist[tid];
        basebkt[tid] = tid * CAP + (h ? atomicAdd(&bcur[tid], h) : 0);
    }
    __syncthreads();
    if (tid < 200) hist[tid] = 0;
    __syncthreads();
    for (int e = e0 + tid; e < e1; e += 256) {
        int d = dst[e];
        int bk = d >> 9;
        int o = atomicAdd(&hist[bk], 1);
        ebuf[basebkt[bk] + o] = (src[e] << 9) | (d & 511);
    }
}

// ---------------- per-bucket counting sort -> deg, stv, dinv, adj (bucketed layout)
__launch_bounds__(256)
__global__ void k_bsort(const int* __restrict__ ebuf, const int* __restrict__ bcur,
                        int* __restrict__ adj, int* __restrict__ stv,
                        int* __restrict__ deg, float* __restrict__ dinv, int N) {
    __shared__ int cnt[512];
    __shared__ int offs[512];
    const int b = blockIdx.x;
    const int tid = threadIdx.x;
    const int base = b * CAP;
    const int n_b = min(bcur[b], CAP);
    const int node0 = b << 9;
    cnt[tid] = 0; cnt[tid + 256] = 0;
    __syncthreads();
    for (int i = tid; i < n_b; i += 256)
        atomicAdd(&cnt[ebuf[base + i] & 511], 1);
    __syncthreads();
    if (tid < 64) {  // wave-0 exclusive scan of 512
        int v[8], tot = 0;
#pragma unroll
        for (int j = 0; j < 8; ++j) { int t = cnt[tid * 8 + j]; v[j] = tot; tot += t; }
        int inc = tot;
#pragma unroll
        for (int d = 1; d < 64; d <<= 1) {
            int u = __shfl_up(inc, d, 64);
            if (tid >= d) inc += u;
        }
        const int excl = inc - tot;
#pragma unroll
        for (int j = 0; j < 8; ++j) offs[tid * 8 + j] = excl + v[j];
    }
    __syncthreads();
#pragma unroll
    for (int h = 0; h < 2; ++h) {
        int local = tid + h * 256;
        int node = node0 + local;
        if (node < N) {
            stv[node] = base + offs[local];
            deg[node] = cnt[local];
            dinv[node] = rsqrtf((float)(cnt[local] + 1));
        }
    }
    __syncthreads();
    for (int i = tid; i < n_b; i += 256) {  // offs doubles as cursor
        int pk = ebuf[base + i];
        int pos = atomicAdd(&offs[pk & 511], 1);
        adj[base + pos] = pk >> 9;
    }
}

// ---------------- MFMA GEMM: tp[i][:] = fp16( dinv[i] * (X[i][:] @ W) ), K=128
template <int BN, bool AFP16>
__launch_bounds__(256, 4)
__global__ void k_gemm_mfma(const void* __restrict__ Xv, const _Float16* __restrict__ wsz,
                            const float* __restrict__ dinv, __half* __restrict__ out, int N) {
    constexpr int NT = BN / 16;
    constexpr int PAD = 8;
    __shared__ __align__(16) _Float16 smem[BN * 128];  // B frags; reused for epilogue

    const int tid = threadIdx.x;
    for (int i = tid; i < BN * 16; i += 256)
        *(uint4*)&smem[i << 3] = *(const uint4*)&wsz[i << 3];

    const int w = tid >> 6;
    const int lane = tid & 63;
    const int q = lane >> 4;
    const int m = lane & 15;
    const int row0 = blockIdx.x * 64;
    const int arow = row0 + w * 16 + m;
    const int arowc = arow < N ? arow : N - 1;

    float4v acc[NT];
#pragma unroll
    for (int nt = 0; nt < NT; ++nt) acc[nt] = (float4v){0.f, 0.f, 0.f, 0.f};

    __syncthreads();

#pragma unroll
    for (int kblk = 0; kblk < 4; ++kblk) {
        half8 af;
        if constexpr (AFP16) {
            const _Float16* A = (const _Float16*)Xv + (size_t)arowc * 128 + (q << 3);
            af = *(const half8*)(A + kblk * 32);
        } else {
            const float* A = (const float*)Xv + (size_t)arowc * 128 + (q << 3);
            float4 a0 = *(const float4*)(A + kblk * 32);
            float4 a1 = *(const float4*)(A + kblk * 32 + 4);
            af[0] = (_Float16)a0.x; af[1] = (_Float16)a0.y;
            af[2] = (_Float16)a0.z; af[3] = (_Float16)a0.w;
            af[4] = (_Float16)a1.x; af[5] = (_Float16)a1.y;
            af[6] = (_Float16)a1.z; af[7] = (_Float16)a1.w;
        }
#pragma unroll
        for (int nt = 0; nt < NT; ++nt) {
            half8 bf = *(const half8*)&smem[(((nt << 2) + kblk) << 9) + (lane << 3)];
            acc[nt] = __builtin_amdgcn_mfma_f32_16x16x32_f16(af, bf, acc[nt], 0, 0, 0);
        }
    }

    float s[4];
#pragma unroll
    for (int r = 0; r < 4; ++r) {
        int rr = row0 + w * 16 + q * 4 + r;
        s[r] = dinv[rr < N ? rr : N - 1];
    }
    __syncthreads();  // all B reads done before smem reuse
    _Float16* eb = smem;
#pragma unroll
    for (int nt = 0; nt < NT; ++nt)
#pragma unroll
        for (int r = 0; r < 4; ++r)
            eb[(w * 16 + q * 4 + r) * (BN + PAD) + nt * 16 + m] = (_Float16)(acc[nt][r] * s[r]);
    __syncthreads();
    constexpr int CPR = BN / 8;
    for (int i = tid; i < 64 * CPR; i += 256) {
        int row = i / CPR;
        int cf = (i % CPR) * 8;
        if (row0 + row < N)
            *(uint4*)&out[(size_t)(row0 + row) * BN + cf] = *(uint4*)&eb[row * (BN + PAD) + cf];
    }
}

// ---------------- FUSED d=128 agg + bias + relu + GEMM(W_next, BN) -> tp_next
// 512 threads = 8 waves; 16 nodes/block (2 per wave, identical inner loop to the
// proven 65us agg). h rows staged in LDS (16x136 fp16), then wave w computes
// GEMM ntile w: tp_next[n] = fp16(dinv[n] * (h[n] @ W)). Deletes the standalone
// GEMM dispatch and the hbuf write+read round-trip per layer boundary.
template <int BN>
__launch_bounds__(512)
__global__ void k_aggemm(const __half* __restrict__ tp, const int* __restrict__ adj,
                         const int* __restrict__ startv, const int* __restrict__ deg,
                         const float* __restrict__ dinv, const float* __restrict__ bias,
                         const _Float16* __restrict__ wsz, __half* __restrict__ outtp, int N) {
    __shared__ __align__(16) _Float16 hl[16][136];   // 16 h rows, +8 pad
    const int tid = threadIdx.x;
    const int w = tid >> 6;
    const int lane = tid & 63;
    const int blk0 = blockIdx.x << 4;   // 16 nodes per block (N = 6250*16 exactly)
    const int n0 = blk0 + (w << 1);
    const bool v0 = n0 < N;
    const bool v1 = (n0 + 1) < N;
    const int nn0 = v0 ? n0 : 0;
    const int nn1 = v1 ? n0 + 1 : nn0;
    const int s0 = v0 ? startv[nn0] : 0, s1 = v1 ? startv[nn1] : 0;
    const int c0 = v0 ? deg[nn0] : 0;
    const int c1 = v1 ? deg[nn1] : 0;
    const float one = 1.0f;
    const int g = lane >> 4;        // edge group 0..3
    const int sl = lane & 15;       // 16 B chunk within row
    const uint4* rowb = (const uint4*)tp;   // row stride = 16 uint4 (256 B)

    float a0[8] = {0.f, 0.f, 0.f, 0.f, 0.f, 0.f, 0.f, 0.f};
    float a1[8] = {0.f, 0.f, 0.f, 0.f, 0.f, 0.f, 0.f, 0.f};
    auto addrow = [&](float* acc, uint4 v) {
        fmix_lo(acc[0], v.x, one); fmix_hi(acc[1], v.x, one);
        fmix_lo(acc[2], v.y, one); fmix_hi(acc[3], v.y, one);
        fmix_lo(acc[4], v.z, one); fmix_hi(acc[5], v.z, one);
        fmix_lo(acc[6], v.w, one); fmix_hi(acc[7], v.w, one);
    };

    // self-loops
    if (v0) {
        uint4 r0 = rowb[(size_t)nn0 * 16 + sl];
        uint4 r1 = rowb[(size_t)nn1 * 16 + sl];
        if (g == 0) { addrow(a0, r0); if (v1) addrow(a1, r1); }
    }

    // joint main loop: 8 row-gathers in flight per lane
    int e = 0;
    const int mc = min(c0, c1);
    for (; e + 16 <= mc; e += 16) {
        int j0[4], j1[4];
#pragma unroll
        for (int u = 0; u < 4; ++u) { j0[u] = adj[s0 + e + 4 * u + g]; j1[u] = adj[s1 + e + 4 * u + g]; }
        uint4 v0v[4], v1v[4];
#pragma unroll
        for (int u = 0; u < 4; ++u) { v0v[u] = rowb[(size_t)j0[u] * 16 + sl]; v1v[u] = rowb[(size_t)j1[u] * 16 + sl]; }
#pragma unroll
        for (int u = 0; u < 4; ++u) { addrow(a0, v0v[u]); addrow(a1, v1v[u]); }
    }

    auto finish = [&](float* acc, int s, int cnt, int eS) {
        int ee = eS;
        for (; ee + 16 <= cnt; ee += 16) {
            int j[4];
#pragma unroll
            for (int u = 0; u < 4; ++u) j[u] = adj[s + ee + 4 * u + g];
            uint4 v[4];
#pragma unroll
            for (int u = 0; u < 4; ++u) v[u] = rowb[(size_t)j[u] * 16 + sl];
#pragma unroll
            for (int u = 0; u < 4; ++u) addrow(acc, v[u]);
        }
        if (ee + 8 <= cnt) {
            int j[2];
#pragma unroll
            for (int u = 0; u < 2; ++u) j[u] = adj[s + ee + 4 * u + g];
            uint4 v[2];
#pragma unroll
            for (int u = 0; u < 2; ++u) v[u] = rowb[(size_t)j[u] * 16 + sl];
#pragma unroll
            for (int u = 0; u < 2; ++u) addrow(acc, v[u]);
            ee += 8;
        }
        if (ee + 4 <= cnt) {
            addrow(acc, rowb[(size_t)adj[s + ee + g] * 16 + sl]);
            ee += 4;
        }
        if (ee + g < cnt)
            addrow(acc, rowb[(size_t)adj[s + ee + g] * 16 + sl]);
    };
    finish(a0, s0, c0, e);
    if (v1) finish(a1, s1, c1, e);

#pragma unroll
    for (int i = 0; i < 8; ++i) {
        a0[i] += __shfl_xor(a0[i], 32);
        a0[i] += __shfl_xor(a0[i], 16);
        a1[i] += __shfl_xor(a1[i], 32);
        a1[i] += __shfl_xor(a1[i], 16);
    }
    if (g == 0 && v0) {
        float4 b0 = *(const float4*)&bias[sl * 8];
        float4 b1 = *(const float4*)&bias[sl * 8 + 4];
        const float di0 = dinv[nn0];
        float o[8];
        o[0] = fmaxf(di0 * a0[0] + b0.x, 0.f); o[1] = fmaxf(di0 * a0[1] + b0.y, 0.f);
        o[2] = fmaxf(di0 * a0[2] + b0.z, 0.f); o[3] = fmaxf(di0 * a0[3] + b0.w, 0.f);
        o[4] = fmaxf(di0 * a0[4] + b1.x, 0.f); o[5] = fmaxf(di0 * a0[5] + b1.y, 0.f);
        o[6] = fmaxf(di0 * a0[6] + b1.z, 0.f); o[7] = fmaxf(di0 * a0[7] + b1.w, 0.f);
        __half2 ov[4];
#pragma unroll
        for (int i = 0; i < 4; ++i) ov[i] = __floats2half2_rn(o[2 * i], o[2 * i + 1]);
        *(uint4*)&hl[w * 2][sl * 8] = *(uint4*)ov;
        if (v1) {
            const float di1 = dinv[nn1];
            o[0] = fmaxf(di1 * a1[0] + b0.x, 0.f); o[1] = fmaxf(di1 * a1[1] + b0.y, 0.f);
            o[2] = fmaxf(di1 * a1[2] + b0.z, 0.f); o[3] = fmaxf(di1 * a1[3] + b0.w, 0.f);
            o[4] = fmaxf(di1 * a1[4] + b1.x, 0.f); o[5] = fmaxf(di1 * a1[5] + b1.y, 0.f);
            o[6] = fmaxf(di1 * a1[6] + b1.z, 0.f); o[7] = fmaxf(di1 * a1[7] + b1.w, 0.f);
#pragma unroll
            for (int i = 0; i < 4; ++i) ov[i] = __floats2half2_rn(o[2 * i], o[2 * i + 1]);
            *(uint4*)&hl[w * 2 + 1][sl * 8] = *(uint4*)ov;
        }
    }
    __syncthreads();

    // GEMM epilogue: wave w computes ntile w (16 cols) for all 16 rows.
    if (w < BN / 16) {
        const int q = lane >> 4;
        const int m = lane & 15;
        float4v acc = (float4v){0.f, 0.f, 0.f, 0.f};
#pragma unroll
        for (int kblk = 0; kblk < 4; ++kblk) {
            half8 af = *(const half8*)&hl[m][(q << 3) + kblk * 32];
            half8 bf = *(const half8*)&wsz[(((w << 2) + kblk) << 9) + (lane << 3)];
            acc = __builtin_amdgcn_mfma_f32_16x16x32_f16(af, bf, acc, 0, 0, 0);
        }
#pragma unroll
        for (int r = 0; r < 4; ++r) {
            const int row = q * 4 + r;
            const int node = blk0 + row;
            if (node < N)
                outtp[(size_t)node * BN + w * 16 + m] = __float2half(acc[r] * dinv[node]);
        }
    }
}

// ---------------- d=64 aggregation (fp32 out): TWO nodes per wave
__launch_bounds__(256)
__global__ void k_agg64(const __half* __restrict__ tp, const int* __restrict__ adj,
                        const int* __restrict__ startv, const int* __restrict__ deg,
                        const float* __restrict__ dinv, const float* __restrict__ bias,
                        float* __restrict__ out, int N) {
    const int n0 = (blockIdx.x << 3) + ((threadIdx.x >> 6) << 1);
    const int lane = threadIdx.x & 63;
    if (n0 >= N) return;
    const bool has1 = (n0 + 1) < N;
    const int n1 = has1 ? n0 + 1 : n0;
    const int s0 = startv[n0], s1 = startv[n1];
    const int c0 = deg[n0];
    const int c1 = has1 ? deg[n1] : 0;
    const float one = 1.0f;
    const int g = lane >> 4;
    const int sl = lane & 15;
    const uint2* rowb = (const uint2*)tp;   // row stride = 16 uint2 (128 B)

    float a0[4] = {0.f, 0.f, 0.f, 0.f};
    float a1[4] = {0.f, 0.f, 0.f, 0.f};
    auto addrow = [&](float* acc, uint2 v) {
        fmix_lo(acc[0], v.x, one); fmix_hi(acc[1], v.x, one);
        fmix_lo(acc[2], v.y, one); fmix_hi(acc[3], v.y, one);
    };
    {
        uint2 r0 = rowb[(size_t)n0 * 16 + sl];
        uint2 r1 = rowb[(size_t)n1 * 16 + sl];
        if (g == 0) { addrow(a0, r0); if (has1) addrow(a1, r1); }
    }

    int e = 0;
    const int mc = min(c0, c1);
    for (; e + 16 <= mc; e += 16) {
        int j0[4], j1[4];
#pragma unroll
        for (int u = 0; u < 4; ++u) { j0[u] = adj[s0 + e + 4 * u + g]; j1[u] = adj[s1 + e + 4 * u + g]; }
        uint2 v0[4], v1[4];
#pragma unroll
        for (int u = 0; u < 4; ++u) { v0[u] = rowb[(size_t)j0[u] * 16 + sl]; v1[u] = rowb[(size_t)j1[u] * 16 + sl]; }
#pragma unroll
        for (int u = 0; u < 4; ++u) { addrow(a0, v0[u]); addrow(a1, v1[u]); }
    }

    auto finish = [&](float* acc, int s, int cnt, int eS) {
        int ee = eS;
        for (; ee + 16 <= cnt; ee += 16) {
            int j[4];
#pragma unroll
            for (int u = 0; u < 4; ++u) j[u] = adj[s + ee + 4 * u + g];
            uint2 v[4];
#pragma unroll
            for (int u = 0; u < 4; ++u) v[u] = rowb[(size_t)j[u] * 16 + sl];
#pragma unroll
            for (int u = 0; u < 4; ++u) addrow(acc, v[u]);
        }
        if (ee + 8 <= cnt) {
            int j[2];
#pragma unroll
            for (int u = 0; u < 2; ++u) j[u] = adj[s + ee + 4 * u + g];
            uint2 v[2];
#pragma unroll
            for (int u = 0; u < 2; ++u) v[u] = rowb[(size_t)j[u] * 16 + sl];
#pragma unroll
            for (int u = 0; u < 2; ++u) addrow(acc, v[u]);
            ee += 8;
        }
        if (ee + 4 <= cnt) {
            addrow(acc, rowb[(size_t)adj[s + ee + g] * 16 + sl]);
            ee += 4;
        }
        if (ee + g < cnt)
            addrow(acc, rowb[(size_t)adj[s + ee + g] * 16 + sl]);
    };
    finish(a0, s0, c0, e);
    if (has1) finish(a1, s1, c1, e);

#pragma unroll
    for (int i = 0; i < 4; ++i) {
        a0[i] += __shfl_xor(a0[i], 32);
        a0[i] += __shfl_xor(a0[i], 16);
        a1[i] += __shfl_xor(a1[i], 32);
        a1[i] += __shfl_xor(a1[i], 16);
    }
    if (g == 0) {
        float4 bb = *(const float4*)&bias[sl * 4];
        const float di0 = dinv[n0];
        float4 o;
        o.x = di0 * a0[0] + bb.x; o.y = di0 * a0[1] + bb.y;
        o.z = di0 * a0[2] + bb.z; o.w = di0 * a0[3] + bb.w;
        *(float4*)&out[(size_t)n0 * 64 + sl * 4] = o;
        if (has1) {
            const float di1 = dinv[n1];
            o.x = di1 * a1[0] + bb.x; o.y = di1 * a1[1] + bb.y;
            o.z = di1 * a1[2] + bb.z; o.w = di1 * a1[3] + bb.w;
            *(float4*)&out[(size_t)n1 * 64 + sl * 4] = o;
        }
    }
}

extern "C" void kernel_launch(void* const* d_in, const int* in_sizes, int n_in,
                              void* d_out, int out_size, void* d_ws, size_t ws_size,
                              hipStream_t stream) {
    const float* x  = (const float*)d_in[0];
    const int*   ei = (const int*)d_in[1];
    const float* W1 = (const float*)d_in[2];
    const float* b1 = (const float*)d_in[3];
    const float* W2 = (const float*)d_in[4];
    const float* b2 = (const float*)d_in[5];
    const float* W3 = (const float*)d_in[6];
    const float* b3 = (const float*)d_in[7];
    float* out = (float*)d_out;
    const int* src = ei;            // edge_index[0]
    const int* dst = ei + N_EDGES;  // edge_index[1]

    char* p = (char*)d_ws;
    __half* tpA     = (__half*)p;    p += (size_t)N_NODES * 128 * 2;   // 25.6 MB
    __half* tpB     = (__half*)p;    p += (size_t)N_NODES * 128 * 2;   // 25.6 MB
    int*   deg  = (int*)p;    p += (size_t)N_NODES * 4;
    float* dinv = (float*)p;  p += (size_t)N_NODES * 4;
    int*   stv  = (int*)p;    p += (size_t)N_NODES * 4;
    int*   bCur = (int*)p;    p += 1024;                               // bucket fill counts
    int*   adj  = (int*)p;    p += (size_t)NBUCKET * CAP * 4 + 16384;  // 7.0 MB bucketed
    _Float16* wz1 = (_Float16*)p; p += 16384 * 2;                      // 32 KB
    _Float16* wz2 = (_Float16*)p; p += 16384 * 2;                      // 32 KB
    _Float16* wz3 = (_Float16*)p; p += 8192 * 2;                       // 16 KB
    size_t need = (size_t)(p - (char*)d_ws);
    if (ws_size < need) return;  // visible failure rather than OOB

    int* ebuf = (int*)tpA;  // 7.0 MB alias; tpA not live until layer-1 GEMM

    hipMemsetAsync(bCur, 0, 1024, stream);
    k_part_wswz<<<276, 256, 0, stream>>>(src, dst, bCur, ebuf, N_EDGES,
                                         W1, W2, W3, wz1, wz2, wz3);
    k_bsort<<<NBUCKET, 256, 0, stream>>>(ebuf, bCur, adj, stv, deg, dinv, N_NODES);

    const int gb = (N_NODES + 63) / 64;
    const int fb = (N_NODES + 15) / 16;   // 6250 fused agg+gemm blocks (512 thr)
    const int ab = (N_NODES + 7) / 8;
    // layer 1 transform: tpA = fp16(dinv * (x @ W1))
    k_gemm_mfma<128, false><<<gb, 256, 0, stream>>>(x, wz1, dinv, tpA, N_NODES);
    // fused: h1 = relu(dinv*agg(tpA)+b1); tpB = fp16(dinv * (h1 @ W2))
    k_aggemm<128><<<fb, 512, 0, stream>>>(tpA, adj, stv, deg, dinv, b1, wz2, tpB, N_NODES);
    // fused: h2 = relu(dinv*agg(tpB)+b2); tpA = fp16(dinv * (h2 @ W3))  (d=64 rows)
    k_aggemm<64><<<fb, 512, 0, stream>>>(tpB, adj, stv, deg, dinv, b2, wz3, tpA, N_NODES);
    // final: out = dinv*agg(tpA) + b3  (fp32, no relu)
    k_agg64<<<ab, 256, 0, stream>>>(tpA, adj, stv, deg, dinv, b3, out, N_NODES);
}

// Round 8
// 345.227 us; speedup vs baseline: 4.8889x; 1.0255x over previous
//
#include <hip/hip_runtime.h>
#include <hip/hip_fp16.h>

#define N_NODES 100000
#define N_EDGES 1600000
#define NBUCKET 196          // ceil(100000 / 512)
#define CAP     8960         // per-bucket capacity: mean 8163, sigma 90 -> +8.8 sigma
#define EPB     6250         // edges per block in partition (256 blocks)

typedef _Float16 half8 __attribute__((ext_vector_type(8)));
typedef float float4v __attribute__((ext_vector_type(4)));

// acc += (float)lo_half(w)  /  acc += (float)hi_half(w)  in ONE VALU op each.
// v_fma_mix_f32: numerically identical to cvt+add (h exact in f32, x1.0 exact).
__device__ __forceinline__ void fmix_lo(float& a, unsigned int w, float one) {
    asm("v_fma_mix_f32 %0, %1, %2, %0 op_sel:[0,0,0] op_sel_hi:[1,0,0]"
        : "+v"(a) : "v"(w), "v"(one));
}
__device__ __forceinline__ void fmix_hi(float& a, unsigned int w, float one) {
    asm("v_fma_mix_f32 %0, %1, %2, %0 op_sel:[1,0,0] op_sel_hi:[1,0,0]"
        : "+v"(a) : "v"(w), "v"(one));
}

// ---------------- partition edges into fixed-capacity bucket segments
// packed entry: (src << 9) | (dst & 511)  [src < 2^17, bucket-local dst < 2^9]
// Blocks 256..275 instead perform the W->fp16 B-fragment swizzles (fused k_wswz).
__launch_bounds__(256)
__global__ void k_part_wswz(const int* __restrict__ src, const int* __restrict__ dst,
                            int* __restrict__ bcur, int* __restrict__ ebuf, int E,
                            const float* __restrict__ W1, const float* __restrict__ W2,
                            const float* __restrict__ W3, _Float16* __restrict__ wz1,
                            _Float16* __restrict__ wz2, _Float16* __restrict__ wz3) {
    if (blockIdx.x >= 256) {
        // -------- weight swizzle path (20 blocks * 256 = 5120 threads)
        int t = (blockIdx.x - 256) * 256 + threadIdx.x;
        const float* W; _Float16* wsz; int BN;
        if (t < 2048)      { W = W1; wsz = wz1; BN = 128; }
        else if (t < 4096) { W = W2; wsz = wz2; BN = 128; t -= 2048; }
        else if (t < 5120) { W = W3; wsz = wz3; BN = 64;  t -= 4096; }
        else return;
        const int l = t & 63;
        const int kblk = (t >> 6) & 3;
        const int nt = t >> 8;
        const int krow = kblk * 32 + ((l >> 4) << 3);
        const int col = nt * 16 + (l & 15);
        _Float16 v[8];
#pragma unroll
        for (int j = 0; j < 8; ++j) v[j] = (_Float16)W[(krow + j) * BN + col];
        *(uint4*)&wsz[t << 3] = *(uint4*)v;
        return;
    }
    __shared__ int hist[200];
    __shared__ int basebkt[200];
    const int tid = threadIdx.x;
    if (tid < 200) hist[tid] = 0;
    __syncthreads();
    const int e0 = blockIdx.x * EPB, e1 = min(e0 + EPB, E);
    for (int e = e0 + tid; e < e1; e += 256) atomicAdd(&hist[dst[e] >> 9], 1);
    __syncthreads();
    if (tid < NBUCKET) {
        int h = hist[tid];
        basebkt[tid] = tid * CAP + (h ? atomicAdd(&bcur[tid], h) : 0);
    }
    __syncthreads();
    if (tid < 200) hist[tid] = 0;
    __syncthreads();
    for (int e = e0 + tid; e < e1; e += 256) {
        int d = dst[e];
        int bk = d >> 9;
        int o = atomicAdd(&hist[bk], 1);
        ebuf[basebkt[bk] + o] = (src[e] << 9) | (d & 511);
    }
}

// ---------------- per-bucket counting sort -> deg, stv, dinv, adj (bucketed layout)
__launch_bounds__(256)
__global__ void k_bsort(const int* __restrict__ ebuf, const int* __restrict__ bcur,
                        int* __restrict__ adj, int* __restrict__ stv,
                        int* __restrict__ deg, float* __restrict__ dinv, int N) {
    __shared__ int cnt[512];
    __shared__ int offs[512];
    const int b = blockIdx.x;
    const int tid = threadIdx.x;
    const int base = b * CAP;
    const int n_b = min(bcur[b], CAP);
    const int node0 = b << 9;
    cnt[tid] = 0; cnt[tid + 256] = 0;
    __syncthreads();
    for (int i = tid; i < n_b; i += 256)
        atomicAdd(&cnt[ebuf[base + i] & 511], 1);
    __syncthreads();
    if (tid < 64) {  // wave-0 exclusive scan of 512
        int v[8], tot = 0;
#pragma unroll
        for (int j = 0; j < 8; ++j) { int t = cnt[tid * 8 + j]; v[j] = tot; tot += t; }
        int inc = tot;
#pragma unroll
        for (int d = 1; d < 64; d <<= 1) {
            int u = __shfl_up(inc, d, 64);
            if (tid >= d) inc += u;
        }
        const int excl = inc - tot;
#pragma unroll
        for (int j = 0; j < 8; ++j) offs[tid * 8 + j] = excl + v[j];
    }
    __syncthreads();
#pragma unroll
    for (int h = 0; h < 2; ++h) {
        int local = tid + h * 256;
        int node = node0 + local;
        if (node < N) {
            stv[node] = base + offs[local];
            deg[node] = cnt[local];
            dinv[node] = rsqrtf((float)(cnt[local] + 1));
        }
    }
    __syncthreads();
    for (int i = tid; i < n_b; i += 256) {  // offs doubles as cursor
        int pk = ebuf[base + i];
        int pos = atomicAdd(&offs[pk & 511], 1);
        adj[base + pos] = pk >> 9;
    }
}

// ---------------- MFMA GEMM: tp[i][:] = fp16( dinv[i] * (X[i][:] @ W) ), K=128
template <int BN, bool AFP16>
__launch_bounds__(256, 4)
__global__ void k_gemm_mfma(const void* __restrict__ Xv, const _Float16* __restrict__ wsz,
                            const float* __restrict__ dinv, __half* __restrict__ out, int N) {
    constexpr int NT = BN / 16;
    constexpr int PAD = 8;
    __shared__ __align__(16) _Float16 smem[BN * 128];  // B frags; reused for epilogue

    const int tid = threadIdx.x;
    for (int i = tid; i < BN * 16; i += 256)
        *(uint4*)&smem[i << 3] = *(const uint4*)&wsz[i << 3];

    const int w = tid >> 6;
    const int lane = tid & 63;
    const int q = lane >> 4;
    const int m = lane & 15;
    const int row0 = blockIdx.x * 64;
    const int arow = row0 + w * 16 + m;
    const int arowc = arow < N ? arow : N - 1;

    float4v acc[NT];
#pragma unroll
    for (int nt = 0; nt < NT; ++nt) acc[nt] = (float4v){0.f, 0.f, 0.f, 0.f};

    __syncthreads();

#pragma unroll
    for (int kblk = 0; kblk < 4; ++kblk) {
        half8 af;
        if constexpr (AFP16) {
            const _Float16* A = (const _Float16*)Xv + (size_t)arowc * 128 + (q << 3);
            af = *(const half8*)(A + kblk * 32);
        } else {
            const float* A = (const float*)Xv + (size_t)arowc * 128 + (q << 3);
            float4 a0 = *(const float4*)(A + kblk * 32);
            float4 a1 = *(const float4*)(A + kblk * 32 + 4);
            af[0] = (_Float16)a0.x; af[1] = (_Float16)a0.y;
            af[2] = (_Float16)a0.z; af[3] = (_Float16)a0.w;
            af[4] = (_Float16)a1.x; af[5] = (_Float16)a1.y;
            af[6] = (_Float16)a1.z; af[7] = (_Float16)a1.w;
        }
#pragma unroll
        for (int nt = 0; nt < NT; ++nt) {
            half8 bf = *(const half8*)&smem[(((nt << 2) + kblk) << 9) + (lane << 3)];
            acc[nt] = __builtin_amdgcn_mfma_f32_16x16x32_f16(af, bf, acc[nt], 0, 0, 0);
        }
    }

    float s[4];
#pragma unroll
    for (int r = 0; r < 4; ++r) {
        int rr = row0 + w * 16 + q * 4 + r;
        s[r] = dinv[rr < N ? rr : N - 1];
    }
    __syncthreads();  // all B reads done before smem reuse
    _Float16* eb = smem;
#pragma unroll
    for (int nt = 0; nt < NT; ++nt)
#pragma unroll
        for (int r = 0; r < 4; ++r)
            eb[(w * 16 + q * 4 + r) * (BN + PAD) + nt * 16 + m] = (_Float16)(acc[nt][r] * s[r]);
    __syncthreads();
    constexpr int CPR = BN / 8;
    for (int i = tid; i < 64 * CPR; i += 256) {
        int row = i / CPR;
        int cf = (i % CPR) * 8;
        if (row0 + row < N)
            *(uint4*)&out[(size_t)(row0 + row) * BN + cf] = *(uint4*)&eb[row * (BN + PAD) + cf];
    }
}

// ---------------- FUSED d=128 agg + bias + relu + GEMM(W_next, BN) -> tp_next
// 512 threads = 8 waves; 16 nodes/block (2 per wave, identical inner loop to the
// proven 65us agg). h rows staged in LDS (16x136 fp16), then wave w computes
// GEMM ntile w: tp_next[n] = fp16(dinv[n] * (h[n] @ W)). Deletes the standalone
// GEMM dispatch and the hbuf write+read round-trip per layer boundary.
template <int BN>
__launch_bounds__(512)
__global__ void k_aggemm(const __half* __restrict__ tp, const int* __restrict__ adj,
                         const int* __restrict__ startv, const int* __restrict__ deg,
                         const float* __restrict__ dinv, const float* __restrict__ bias,
                         const _Float16* __restrict__ wsz, __half* __restrict__ outtp, int N) {
    __shared__ __align__(16) _Float16 hl[16][136];   // 16 h rows, +8 pad
    const int tid = threadIdx.x;
    const int w = tid >> 6;
    const int lane = tid & 63;
    const int blk0 = blockIdx.x << 4;   // 16 nodes per block (N = 6250*16 exactly)
    const int n0 = blk0 + (w << 1);
    const bool v0 = n0 < N;
    const bool v1 = (n0 + 1) < N;
    const int nn0 = v0 ? n0 : 0;
    const int nn1 = v1 ? n0 + 1 : nn0;
    const int s0 = v0 ? startv[nn0] : 0, s1 = v1 ? startv[nn1] : 0;
    const int c0 = v0 ? deg[nn0] : 0;
    const int c1 = v1 ? deg[nn1] : 0;
    const float one = 1.0f;
    const int g = lane >> 4;        // edge group 0..3
    const int sl = lane & 15;       // 16 B chunk within row
    const uint4* rowb = (const uint4*)tp;   // row stride = 16 uint4 (256 B)

    float a0[8] = {0.f, 0.f, 0.f, 0.f, 0.f, 0.f, 0.f, 0.f};
    float a1[8] = {0.f, 0.f, 0.f, 0.f, 0.f, 0.f, 0.f, 0.f};
    auto addrow = [&](float* acc, uint4 v) {
        fmix_lo(acc[0], v.x, one); fmix_hi(acc[1], v.x, one);
        fmix_lo(acc[2], v.y, one); fmix_hi(acc[3], v.y, one);
        fmix_lo(acc[4], v.z, one); fmix_hi(acc[5], v.z, one);
        fmix_lo(acc[6], v.w, one); fmix_hi(acc[7], v.w, one);
    };

    // self-loops
    if (v0) {
        uint4 r0 = rowb[(size_t)nn0 * 16 + sl];
        uint4 r1 = rowb[(size_t)nn1 * 16 + sl];
        if (g == 0) { addrow(a0, r0); if (v1) addrow(a1, r1); }
    }

    // joint main loop: 8 row-gathers in flight per lane
    int e = 0;
    const int mc = min(c0, c1);
    for (; e + 16 <= mc; e += 16) {
        int j0[4], j1[4];
#pragma unroll
        for (int u = 0; u < 4; ++u) { j0[u] = adj[s0 + e + 4 * u + g]; j1[u] = adj[s1 + e + 4 * u + g]; }
        uint4 v0v[4], v1v[4];
#pragma unroll
        for (int u = 0; u < 4; ++u) { v0v[u] = rowb[(size_t)j0[u] * 16 + sl]; v1v[u] = rowb[(size_t)j1[u] * 16 + sl]; }
#pragma unroll
        for (int u = 0; u < 4; ++u) { addrow(a0, v0v[u]); addrow(a1, v1v[u]); }
    }

    auto finish = [&](float* acc, int s, int cnt, int eS) {
        int ee = eS;
        for (; ee + 16 <= cnt; ee += 16) {
            int j[4];
#pragma unroll
            for (int u = 0; u < 4; ++u) j[u] = adj[s + ee + 4 * u + g];
            uint4 v[4];
#pragma unroll
            for (int u = 0; u < 4; ++u) v[u] = rowb[(size_t)j[u] * 16 + sl];
#pragma unroll
            for (int u = 0; u < 4; ++u) addrow(acc, v[u]);
        }
        if (ee + 8 <= cnt) {
            int j[2];
#pragma unroll
            for (int u = 0; u < 2; ++u) j[u] = adj[s + ee + 4 * u + g];
            uint4 v[2];
#pragma unroll
            for (int u = 0; u < 2; ++u) v[u] = rowb[(size_t)j[u] * 16 + sl];
#pragma unroll
            for (int u = 0; u < 2; ++u) addrow(acc, v[u]);
            ee += 8;
        }
        if (ee + 4 <= cnt) {
            addrow(acc, rowb[(size_t)adj[s + ee + g] * 16 + sl]);
            ee += 4;
        }
        if (ee + g < cnt)
            addrow(acc, rowb[(size_t)adj[s + ee + g] * 16 + sl]);
    };
    finish(a0, s0, c0, e);
    if (v1) finish(a1, s1, c1, e);

#pragma unroll
    for (int i = 0; i < 8; ++i) {
        a0[i] += __shfl_xor(a0[i], 32);
        a0[i] += __shfl_xor(a0[i], 16);
        a1[i] += __shfl_xor(a1[i], 32);
        a1[i] += __shfl_xor(a1[i], 16);
    }
    if (g == 0 && v0) {
        float4 b0 = *(const float4*)&bias[sl * 8];
        float4 b1 = *(const float4*)&bias[sl * 8 + 4];
        const float di0 = dinv[nn0];
        float o[8];
        o[0] = fmaxf(di0 * a0[0] + b0.x, 0.f); o[1] = fmaxf(di0 * a0[1] + b0.y, 0.f);
        o[2] = fmaxf(di0 * a0[2] + b0.z, 0.f); o[3] = fmaxf(di0 * a0[3] + b0.w, 0.f);
        o[4] = fmaxf(di0 * a0[4] + b1.x, 0.f); o[5] = fmaxf(di0 * a0[5] + b1.y, 0.f);
        o[6] = fmaxf(di0 * a0[6] + b1.z, 0.f); o[7] = fmaxf(di0 * a0[7] + b1.w, 0.f);
        __half2 ov[4];
#pragma unroll
        for (int i = 0; i < 4; ++i) ov[i] = __floats2half2_rn(o[2 * i], o[2 * i + 1]);
        *(uint4*)&hl[w * 2][sl * 8] = *(uint4*)ov;
        if (v1) {
            const float di1 = dinv[nn1];
            o[0] = fmaxf(di1 * a1[0] + b0.x, 0.f); o[1] = fmaxf(di1 * a1[1] + b0.y, 0.f);
            o[2] = fmaxf(di1 * a1[2] + b0.z, 0.f); o[3] = fmaxf(di1 * a1[3] + b0.w, 0.f);
            o[4] = fmaxf(di1 * a1[4] + b1.x, 0.f); o[5] = fmaxf(di1 * a1[5] + b1.y, 0.f);
            o[6] = fmaxf(di1 * a1[6] + b1.z, 0.f); o[7] = fmaxf(di1 * a1[7] + b1.w, 0.f);
#pragma unroll
            for (int i = 0; i < 4; ++i) ov[i] = __floats2half2_rn(o[2 * i], o[2 * i + 1]);
            *(uint4*)&hl[w * 2 + 1][sl * 8] = *(uint4*)ov;
        }
    }
    __syncthreads();

    // GEMM epilogue: wave w computes ntile w (16 cols) for all 16 rows.
    if (w < BN / 16) {
        const int q = lane >> 4;
        const int m = lane & 15;
        float4v acc = (float4v){0.f, 0.f, 0.f, 0.f};
#pragma unroll
        for (int kblk = 0; kblk < 4; ++kblk) {
            half8 af = *(const half8*)&hl[m][(q << 3) + kblk * 32];
            half8 bf = *(const half8*)&wsz[(((w << 2) + kblk) << 9) + (lane << 3)];
            acc = __builtin_amdgcn_mfma_f32_16x16x32_f16(af, bf, acc, 0, 0, 0);
        }
#pragma unroll
        for (int r = 0; r < 4; ++r) {
            const int row = q * 4 + r;
            const int node = blk0 + row;
            if (node < N)
                outtp[(size_t)node * BN + w * 16 + m] = __float2half(acc[r] * dinv[node]);
        }
    }
}

// ---------------- d=64 aggregation (fp32 out): 8 lanes/row x 8 row-slots.
// 128-B rows loaded as uint4 by 8 lanes -> 8 rows per load instruction (2x fewer
// gather instructions than the uint2/16-lane layout, same bytes & in-flight rows).
// Lanes 0-31 = node0 (slots 0-3), lanes 32-63 = node1. Edge->slot mapping and the
// 4-partial reduction tree match the old kernel exactly -> bit-identical output.
__launch_bounds__(256)
__global__ void k_agg64(const __half* __restrict__ tp, const int* __restrict__ adj,
                        const int* __restrict__ startv, const int* __restrict__ deg,
                        const float* __restrict__ dinv, const float* __restrict__ bias,
                        float* __restrict__ out, int N) {
    const int n0 = (blockIdx.x << 3) + ((threadIdx.x >> 6) << 1);
    const int lane = threadIdx.x & 63;
    if (n0 >= N) return;
    const bool has1 = (n0 + 1) < N;
    const int n1 = has1 ? n0 + 1 : n0;
    const int lane8 = lane >> 3;        // row slot 0..7
    const bool first = lane8 < 4;       // half: node0 vs node1
    const int slot = lane8 & 3;         // edge slot within half (matches old g)
    const int sl = lane & 7;            // 16-B chunk within 128-B row
    const int s_h = first ? startv[n0] : startv[n1];
    const int c_h = first ? deg[n0] : (has1 ? deg[n1] : 0);
    const int c0 = deg[n0];
    const int c1 = has1 ? deg[n1] : 0;
    const float one = 1.0f;
    const uint4* rowb = (const uint4*)tp;   // row stride = 8 uint4 (128 B)

    float acc[8] = {0.f, 0.f, 0.f, 0.f, 0.f, 0.f, 0.f, 0.f};
    auto addrow = [&](uint4 v) {
        fmix_lo(acc[0], v.x, one); fmix_hi(acc[1], v.x, one);
        fmix_lo(acc[2], v.y, one); fmix_hi(acc[3], v.y, one);
        fmix_lo(acc[4], v.z, one); fmix_hi(acc[5], v.z, one);
        fmix_lo(acc[6], v.w, one); fmix_hi(acc[7], v.w, one);
    };

    // self-loop: slot 0 of each half (first so ordering matches old kernel)
    {
        const int n_h = first ? n0 : n1;
        uint4 r = rowb[(size_t)n_h * 8 + sl];
        if (slot == 0 && (first || has1)) addrow(r);
    }

    // joint main loop: 32 edges (16/node) per iteration, 4 load instructions
    int e = 0;
    const int mc = min(c0, c1);
    for (; e + 16 <= mc; e += 16) {
        int j[4];
#pragma unroll
        for (int u = 0; u < 4; ++u) j[u] = adj[s_h + e + 4 * u + slot];
        uint4 v[4];
#pragma unroll
        for (int u = 0; u < 4; ++u) v[u] = rowb[(size_t)j[u] * 8 + sl];
#pragma unroll
        for (int u = 0; u < 4; ++u) addrow(v[u]);
    }
    // per-half remainder (exec-masked divergence between halves)
    for (; e + 8 <= c_h; e += 8) {
        int ja = adj[s_h + e + slot];
        int jb = adj[s_h + e + 4 + slot];
        uint4 va = rowb[(size_t)ja * 8 + sl];
        uint4 vb = rowb[(size_t)jb * 8 + sl];
        addrow(va); addrow(vb);
    }
    if (e + 4 <= c_h) {
        addrow(rowb[(size_t)adj[s_h + e + slot] * 8 + sl]);
        e += 4;
    }
    if (e + slot < c_h)
        addrow(rowb[(size_t)adj[s_h + e + slot] * 8 + sl]);

    // reduce 4 slot-partials within each half: (p0+p2)+(p1+p3), same tree as old
#pragma unroll
    for (int i = 0; i < 8; ++i) {
        acc[i] += __shfl_xor(acc[i], 16);
        acc[i] += __shfl_xor(acc[i], 8);
    }
    if (slot == 0 && (first || has1)) {   // lanes 0-7 (node0), 32-39 (node1)
        const int n_h = first ? n0 : n1;
        const float di = dinv[n_h];
        float4 ba = *(const float4*)&bias[sl * 8];
        float4 bb = *(const float4*)&bias[sl * 8 + 4];
        float4 o0, o1;
        o0.x = di * acc[0] + ba.x; o0.y = di * acc[1] + ba.y;
        o0.z = di * acc[2] + ba.z; o0.w = di * acc[3] + ba.w;
        o1.x = di * acc[4] + bb.x; o1.y = di * acc[5] + bb.y;
        o1.z = di * acc[6] + bb.z; o1.w = di * acc[7] + bb.w;
        *(float4*)&out[(size_t)n_h * 64 + sl * 8] = o0;
        *(float4*)&out[(size_t)n_h * 64 + sl * 8 + 4] = o1;
    }
}

extern "C" void kernel_launch(void* const* d_in, const int* in_sizes, int n_in,
                              void* d_out, int out_size, void* d_ws, size_t ws_size,
                              hipStream_t stream) {
    const float* x  = (const float*)d_in[0];
    const int*   ei = (const int*)d_in[1];
    const float* W1 = (const float*)d_in[2];
    const float* b1 = (const float*)d_in[3];
    const float* W2 = (const float*)d_in[4];
    const float* b2 = (const float*)d_in[5];
    const float* W3 = (const float*)d_in[6];
    const float* b3 = (const float*)d_in[7];
    float* out = (float*)d_out;
    const int* src = ei;            // edge_index[0]
    const int* dst = ei + N_EDGES;  // edge_index[1]

    char* p = (char*)d_ws;
    __half* tpA     = (__half*)p;    p += (size_t)N_NODES * 128 * 2;   // 25.6 MB
    __half* tpB     = (__half*)p;    p += (size_t)N_NODES * 128 * 2;   // 25.6 MB
    int*   deg  = (int*)p;    p += (size_t)N_NODES * 4;
    float* dinv = (float*)p;  p += (size_t)N_NODES * 4;
    int*   stv  = (int*)p;    p += (size_t)N_NODES * 4;
    int*   bCur = (int*)p;    p += 1024;                               // bucket fill counts
    int*   adj  = (int*)p;    p += (size_t)NBUCKET * CAP * 4 + 16384;  // 7.0 MB bucketed
    _Float16* wz1 = (_Float16*)p; p += 16384 * 2;                      // 32 KB
    _Float16* wz2 = (_Float16*)p; p += 16384 * 2;                      // 32 KB
    _Float16* wz3 = (_Float16*)p; p += 8192 * 2;                       // 16 KB
    size_t need = (size_t)(p - (char*)d_ws);
    if (ws_size < need) return;  // visible failure rather than OOB

    int* ebuf = (int*)tpA;  // 7.0 MB alias; tpA not live until layer-1 GEMM

    hipMemsetAsync(bCur, 0, 1024, stream);
    k_part_wswz<<<276, 256, 0, stream>>>(src, dst, bCur, ebuf, N_EDGES,
                                         W1, W2, W3, wz1, wz2, wz3);
    k_bsort<<<NBUCKET, 256, 0, stream>>>(ebuf, bCur, adj, stv, deg, dinv, N_NODES);

    const int gb = (N_NODES + 63) / 64;
    const int fb = (N_NODES + 15) / 16;   // 6250 fused agg+gemm blocks (512 thr)
    const int ab = (N_NODES + 7) / 8;
    // layer 1 transform: tpA = fp16(dinv * (x @ W1))
    k_gemm_mfma<128, false><<<gb, 256, 0, stream>>>(x, wz1, dinv, tpA, N_NODES);
    // fused: h1 = relu(dinv*agg(tpA)+b1); tpB = fp16(dinv * (h1 @ W2))
    k_aggemm<128><<<fb, 512, 0, stream>>>(tpA, adj, stv, deg, dinv, b1, wz2, tpB, N_NODES);
    // fused: h2 = relu(dinv*agg(tpB)+b2); tpA = fp16(dinv * (h2 @ W3))  (d=64 rows)
    k_aggemm<64><<<fb, 512, 0, stream>>>(tpB, adj, stv, deg, dinv, b2, wz3, tpA, N_NODES);
    // final: out = dinv*agg(tpA) + b3  (fp32, no relu)
    k_agg64<<<ab, 256, 0, stream>>>(tpA, adj, stv, deg, dinv, b3, out, N_NODES);
}